// Round 3
// baseline (524.032 us; speedup 1.0000x reference)
//
#include <hip/hip_runtime.h>
#include <hip/hip_bf16.h>
#include <cstdint>

// Problem constants (fixed by reference)
#define BATCH 32
#define NCH 3
#define HW 147456            // 384*384
#define NSEG 256
#define NPIX 400             // capacity per segment
#define KDIM 1200            // NCH*NPIX
#define EDIM 768
#define MROWS (BATCH * NSEG) // 8192

#define CHUNK 4096
#define NCHUNK (HW / CHUNK)  // 36

#define FEATS_BYTES ((size_t)BATCH * NSEG * KDIM * 4) // 39,321,600
#define CNT_ELEMS   (BATCH * NCHUNK * NSEG)           // 294,912 ints

// ---------------- Phase 1a: per-chunk histograms ----------------
__global__ __launch_bounds__(256) void hist_kernel(const int* __restrict__ seg,
                                                   int* __restrict__ cnt) {
    __shared__ int h[NSEG];
    const int tid = threadIdx.x;
    h[tid] = 0;
    __syncthreads();
    const int blk = blockIdx.x;            // b*NCHUNK + ck
    const int b = blk / NCHUNK, ck = blk % NCHUNK;
    const int* segb = seg + (size_t)b * HW + ck * CHUNK;
#pragma unroll
    for (int i = 0; i < CHUNK / 256; ++i) {
        atomicAdd(&h[segb[i * 256 + tid]], 1);
    }
    __syncthreads();
    cnt[blk * NSEG + tid] = h[tid];
}

// ---------------- Phase 1b: exclusive scan over chunks per (b, s) ----------------
__global__ __launch_bounds__(256) void scan_kernel(int* __restrict__ cnt) {
    const int t = blockIdx.x * 256 + threadIdx.x;  // 0 .. BATCH*NSEG-1
    const int b = t >> 8, s = t & 255;
    int run = 0;
#pragma unroll
    for (int ck = 0; ck < NCHUNK; ++ck) {
        int* p = cnt + ((size_t)(b * NCHUNK + ck)) * NSEG + s;
        int v = *p;
        *p = run;
        run += v;
    }
}

// ---------------- Phase 1c: scatter with exact scan-order ranks ----------------
// One wave (64 lanes) per 4096-pixel chunk; sequential 64-pixel groups keep
// scan order; within-group ranks via 8-bit ballot match.
__global__ __launch_bounds__(64) void scatter_kernel(const float* __restrict__ img,
                                                     const int* __restrict__ seg,
                                                     const int* __restrict__ base,
                                                     float* __restrict__ feats) {
    const int blk = blockIdx.x;            // b*NCHUNK + ck
    const int b = blk / NCHUNK, ck = blk % NCHUNK;
    const int lane = threadIdx.x;

    __shared__ int cnt[NSEG];
#pragma unroll
    for (int j = 0; j < NSEG / 64; ++j)
        cnt[j * 64 + lane] = base[(size_t)blk * NSEG + j * 64 + lane];
    __syncthreads();

    const int chunkStart = ck * CHUNK;
    const int* segb = seg + (size_t)b * HW;
    const float* imgb = img + (size_t)b * NCH * HW;
    float* fb = feats + (size_t)b * NSEG * KDIM;
    const unsigned long long lt = (lane == 0) ? 0ull : ((~0ull) >> (64 - lane));

    for (int it = 0; it < CHUNK / 64; ++it) {
        const int p = chunkStart + it * 64 + lane;
        const int s = segb[p];
        unsigned long long m = ~0ull;
#pragma unroll
        for (int bit = 0; bit < 8; ++bit) {
            unsigned long long bal = __ballot((s >> bit) & 1);
            m &= ((s >> bit) & 1) ? bal : ~bal;
        }
        const int rig = __popcll(m & lt);          // rank within this 64-group
        const int leader = __ffsll((unsigned long long)m) - 1;
        int old = 0;
        if (rig == 0) old = atomicAdd(&cnt[s], __popcll(m));
        old = __shfl(old, leader, 64);
        const int rank = old + rig;
        if (rank < NPIX) {
            float* dst = fb + (size_t)s * KDIM + rank;
            dst[0]          = imgb[p];
            dst[NPIX]       = imgb[HW + p];
            dst[2 * NPIX]   = imgb[2 * HW + p];
        }
    }
}

// ---------------- Phase 2: GEMM  out[m][e] = sum_k feats[m][k]*W[e][k] + b[e] ----------------
// M=8192, N=768, K=1200.  Tile 128x64, BK=16, 256 threads, 8x4 micro-tile.
// grid 64x12 = 768 blocks -> 3 blocks/CU on 256 CUs.
#define TM 128
#define TN 64
#define BK 16
#define LDA_P 132   // padded LDS row length for As[k][*] (128+4: breaks pow2 stride)
#define LDB_P 68

__global__ __launch_bounds__(256) void gemm_kernel(const float* __restrict__ A,
                                                   const float* __restrict__ W,
                                                   const float* __restrict__ bias,
                                                   float* __restrict__ out) {
    __shared__ float As[BK][LDA_P];
    __shared__ float Bs[BK][LDB_P];

    const int tid = threadIdx.x;
    const int tx = tid & 15;   // n dir (x4)
    const int ty = tid >> 4;   // m dir (x8)
    const int bm = blockIdx.x; // 0..63
    const int bn = blockIdx.y; // 0..11

    const float* Ab = A + (size_t)bm * TM * KDIM;
    const float* Bb = W + (size_t)bn * TN * KDIM;

    float acc[8][4] = {};

    for (int k0 = 0; k0 < KDIM; k0 += BK) {
        // stage A: 128 rows x 16 k = 512 float4, 2 per thread (coalesced 64B/row)
#pragma unroll
        for (int j = 0; j < 2; ++j) {
            const int idx = j * 256 + tid;
            const int row = idx >> 2, kq = idx & 3;
            const float4 v = *(const float4*)(Ab + (size_t)row * KDIM + k0 + kq * 4);
            As[kq * 4 + 0][row] = v.x;
            As[kq * 4 + 1][row] = v.y;
            As[kq * 4 + 2][row] = v.z;
            As[kq * 4 + 3][row] = v.w;
        }
        // stage B: 64 rows x 16 k = 256 float4, 1 per thread
        {
            const int row = tid >> 2, kq = tid & 3;
            const float4 v = *(const float4*)(Bb + (size_t)row * KDIM + k0 + kq * 4);
            Bs[kq * 4 + 0][row] = v.x;
            Bs[kq * 4 + 1][row] = v.y;
            Bs[kq * 4 + 2][row] = v.z;
            Bs[kq * 4 + 3][row] = v.w;
        }
        __syncthreads();

#pragma unroll
        for (int kk = 0; kk < BK; ++kk) {
            const float4 a0 = *(const float4*)&As[kk][ty * 8];
            const float4 a1 = *(const float4*)&As[kk][ty * 8 + 4];
            const float4 b0 = *(const float4*)&Bs[kk][tx * 4];
            const float am[8] = {a0.x, a0.y, a0.z, a0.w, a1.x, a1.y, a1.z, a1.w};
            const float bn4[4] = {b0.x, b0.y, b0.z, b0.w};
#pragma unroll
            for (int i = 0; i < 8; ++i)
#pragma unroll
                for (int j = 0; j < 4; ++j)
                    acc[i][j] = fmaf(am[i], bn4[j], acc[i][j]);
        }
        __syncthreads();
    }

    const float4 bv = *(const float4*)(bias + bn * TN + tx * 4);
#pragma unroll
    for (int i = 0; i < 8; ++i) {
        const int m = bm * TM + ty * 8 + i;
        float4 o;
        o.x = acc[i][0] + bv.x;
        o.y = acc[i][1] + bv.y;
        o.z = acc[i][2] + bv.z;
        o.w = acc[i][3] + bv.w;
        *(float4*)(out + (size_t)m * EDIM + bn * TN + tx * 4) = o;
    }
}

// ---------------- launcher ----------------
extern "C" void kernel_launch(void* const* d_in, const int* in_sizes, int n_in,
                              void* d_out, int out_size, void* d_ws, size_t ws_size,
                              hipStream_t stream) {
    const float* img      = (const float*)d_in[0];
    const int*   segments = (const int*)d_in[1];
    const float* proj_w   = (const float*)d_in[2];
    const float* proj_b   = (const float*)d_in[3];
    float* out = (float*)d_out;

    float* feats = (float*)d_ws;
    int*   cnt   = (int*)((char*)d_ws + FEATS_BYTES);

    // zero the padded feature buffer (ws is re-poisoned to 0xAA before every
    // timed launch, so this memset is mandatory every call)
    hipMemsetAsync(feats, 0, FEATS_BYTES, stream);

    hist_kernel<<<BATCH * NCHUNK, 256, 0, stream>>>(segments, cnt);
    scan_kernel<<<MROWS / 256, 256, 0, stream>>>(cnt);
    scatter_kernel<<<BATCH * NCHUNK, 64, 0, stream>>>(img, segments, cnt, feats);

    dim3 grid(MROWS / TM, EDIM / TN);
    gemm_kernel<<<grid, 256, 0, stream>>>(feats, proj_w, proj_b, out);
}

// Round 5
// 403.416 us; speedup vs baseline: 1.2990x; 1.2990x over previous
//
#include <hip/hip_runtime.h>
#include <hip/hip_bf16.h>
#include <cstdint>

// Problem constants (fixed by reference)
#define BATCH 32
#define NCH 3
#define HW 147456            // 384*384
#define NSEG 256
#define NPIX 400
#define KDIM 1200            // NCH*NPIX
#define K_STORE 1200         // A row stride in u32 (keeps ws footprint == round-3 proven)
#define K_LOOP 1216          // BK=64 * 19 iterations; tail [1200,1216) zero-guarded
#define EDIM 768
#define MROWS (BATCH * NSEG) // 8192

#define CHUNK 4096
#define NCHUNK (HW / CHUNK)  // 36
#define SUB 1024             // per-wave sub-chunk (4 waves/block)

#define APK_BYTES ((size_t)MROWS * K_STORE * 4)  // 39,321,600

typedef __attribute__((ext_vector_type(8))) short short8b; // 8 bf16
typedef __attribute__((ext_vector_type(4))) float f32x4;

// ---- split-bf16 helpers: v ≈ hi + lo, each bf16 (RN) ----
__device__ inline uint32_t bf16_rn(float f) {
    uint32_t u = __float_as_uint(f);
    return (u + 0x7fffu + ((u >> 16) & 1u)) >> 16;
}
__device__ inline float bf16_tof(uint32_t h) { return __uint_as_float(h << 16); }
__device__ inline uint32_t pack_split(float v) {
    uint32_t hi = bf16_rn(v);
    uint32_t lo = bf16_rn(v - bf16_tof(hi));
    return (lo << 16) | hi;
}

// ---------------- Phase 1a: per-chunk histograms ----------------
__global__ __launch_bounds__(256) void hist_kernel(const int* __restrict__ seg,
                                                   int* __restrict__ cnt) {
    __shared__ int h[NSEG];
    const int tid = threadIdx.x;
    h[tid] = 0;
    __syncthreads();
    const int blk = blockIdx.x;
    const int b = blk / NCHUNK, ck = blk % NCHUNK;
    const int* segb = seg + (size_t)b * HW + ck * CHUNK;
#pragma unroll
    for (int i = 0; i < CHUNK / 256; ++i) atomicAdd(&h[segb[i * 256 + tid]], 1);
    __syncthreads();
    cnt[blk * NSEG + tid] = h[tid];
}

// ---------------- Phase 1b: exclusive scan over chunks per (b, s) ----------------
__global__ __launch_bounds__(256) void scan_kernel(int* __restrict__ cnt) {
    const int t = blockIdx.x * 256 + threadIdx.x;
    const int b = t >> 8, s = t & 255;
    int run = 0;
#pragma unroll
    for (int ck = 0; ck < NCHUNK; ++ck) {
        int* p = cnt + ((size_t)(b * NCHUNK + ck)) * NSEG + s;
        int v = *p;
        *p = run;
        run += v;
    }
}

// ---------------- Phase 1c: scatter, 4 waves/block, packed split-bf16 output ----------------
__global__ __launch_bounds__(256) void scatter_kernel(const float* __restrict__ img,
                                                      const int* __restrict__ seg,
                                                      const int* __restrict__ base,
                                                      uint32_t* __restrict__ apk) {
    __shared__ int sbase[NSEG];
    __shared__ int wcnt[4][NSEG];
    __shared__ int pos[4][NSEG];
    const int tid = threadIdx.x;
    const int lane = tid & 63;
    const int wid = tid >> 6;
    const int blk = blockIdx.x;
    const int b = blk / NCHUNK, ck = blk % NCHUNK;

    sbase[tid] = base[(size_t)blk * NSEG + tid];
    wcnt[0][tid] = 0; wcnt[1][tid] = 0; wcnt[2][tid] = 0; wcnt[3][tid] = 0;
    __syncthreads();

    const int* segb = seg + (size_t)b * HW;
    const float* imgb = img + (size_t)b * NCH * HW;
    const int startp = ck * CHUNK + wid * SUB;   // wave owns sequential [startp, startp+1024)
    const unsigned long long lt = (lane == 0) ? 0ull : ((~0ull) >> (64 - lane));

    int sv[16];
    unsigned long long mv[16];
    // pass 1: per-wave per-segment counts (stable: waves own disjoint sequential ranges)
#pragma unroll
    for (int g = 0; g < 16; ++g) {
        const int p = startp + g * 64 + lane;
        const int s = segb[p];
        unsigned long long m = ~0ull;
#pragma unroll
        for (int bit = 0; bit < 8; ++bit) {
            unsigned long long bal = __ballot((s >> bit) & 1);
            m &= ((s >> bit) & 1) ? bal : ~bal;
        }
        sv[g] = s; mv[g] = m;
        if ((m & lt) == 0ull) atomicAdd(&wcnt[wid][s], __popcll(m));
    }
    __syncthreads();
    // per-segment prefix across the 4 waves (thread tid handles segment tid)
    {
        const int s = tid;
        int r = sbase[s];
        pos[0][s] = r; r += wcnt[0][s];
        pos[1][s] = r; r += wcnt[1][s];
        pos[2][s] = r; r += wcnt[2][s];
        pos[3][s] = r;
    }
    __syncthreads();

    // pass 2: assign ranks (in-order g-loop within wave => stable), write packed split-bf16
#pragma unroll
    for (int g = 0; g < 16; ++g) {
        const int p = startp + g * 64 + lane;
        const int s = sv[g];
        const unsigned long long m = mv[g];
        const int rig = __popcll(m & lt);
        const int leader = __ffsll((unsigned long long)m) - 1;
        int old = 0;
        if (rig == 0) old = atomicAdd(&pos[wid][s], __popcll(m));
        old = __shfl(old, leader, 64);
        const int rank = old + rig;
        if (rank < NPIX) {
            uint32_t* dst = apk + (size_t)(b * NSEG + s) * K_STORE + rank;
            dst[0]        = pack_split(imgb[p]);
            dst[NPIX]     = pack_split(imgb[HW + p]);
            dst[2 * NPIX] = pack_split(imgb[2 * HW + p]);
        }
    }
}

// ---------------- Phase 2: split-bf16 MFMA GEMM ----------------
// out[m][e] = sum_k A[m][k]*W[e][k] + bias[e];  A packed u32 = (lo<<16)|hi bf16.
// Block 128x64, 4 waves (2x2), wave tile 64x32 (4x2 of 16x16), BK=64 (2 MFMA k-steps).
#define GBM 128
#define GBN 64
#define BKG 64
#define LDSW 32  // dwords per LDS row (64 bf16)

__device__ inline int swz(int r, int c) { return r * LDSW + (c ^ ((r & 7) << 2)); }

__global__ __launch_bounds__(256) void gemm_kernel(const uint32_t* __restrict__ apk,
                                                   const float* __restrict__ W,
                                                   const float* __restrict__ bias,
                                                   float* __restrict__ out) {
    __shared__ uint32_t AsHi[GBM * LDSW], AsLo[GBM * LDSW];
    __shared__ uint32_t BsHi[GBN * LDSW], BsLo[GBN * LDSW];

    const int tid = threadIdx.x;
    const int lane = tid & 63;
    const int wid = tid >> 6;
    const int wm = wid >> 1, wn = wid & 1;
    const int fr = lane & 15, kg4 = lane >> 4;
    const int bm = blockIdx.x, bn = blockIdx.y;

    const int ar = tid >> 1, ah = tid & 1;   // A-stage: 2 thr/row, 32 u32 each
    const int br = tid >> 2, bq = tid & 3;   // B-stage: 4 thr/row, 16 f32 each
    const uint32_t* arow0 = apk + (size_t)(bm * GBM + ar) * K_STORE;
    const float* wrow0 = W + (size_t)(bn * GBN + br) * KDIM;

    f32x4 acc[4][2] = {};

    for (int k0 = 0; k0 < K_LOOP; k0 += BKG) {
        // ---- stage A: packed u32 -> hi/lo bf16 LDS tiles (swizzled), K-tail zeroed ----
#pragma unroll
        for (int i = 0; i < 8; ++i) {
            const int kA = k0 + ah * 32 + i * 4;       // multiple of 4; KDIM multiple of 4
            uint4 p = make_uint4(0u, 0u, 0u, 0u);
            if (kA < KDIM) p = *(const uint4*)(arow0 + kA);
            const uint32_t h0 = (p.y << 16) | (p.x & 0xffffu);
            const uint32_t l0 = (p.y & 0xffff0000u) | (p.x >> 16);
            const uint32_t h1 = (p.w << 16) | (p.z & 0xffffu);
            const uint32_t l1 = (p.w & 0xffff0000u) | (p.z >> 16);
            const int idx = swz(ar, ah * 16 + i * 2);
            *(uint2*)&AsHi[idx] = make_uint2(h0, h1);
            *(uint2*)&AsLo[idx] = make_uint2(l0, l1);
        }
        // ---- stage B: f32 W -> hi/lo bf16 (K-tail zeroed) ----
#pragma unroll
        for (int i = 0; i < 4; ++i) {
            const int kB = k0 + bq * 16 + i * 4;
            float4 f = make_float4(0.f, 0.f, 0.f, 0.f);
            if (kB < KDIM) f = *(const float4*)(wrow0 + kB);
            const uint32_t h0 = bf16_rn(f.x), h1 = bf16_rn(f.y),
                           h2 = bf16_rn(f.z), h3 = bf16_rn(f.w);
            const uint32_t l0 = bf16_rn(f.x - bf16_tof(h0)), l1 = bf16_rn(f.y - bf16_tof(h1)),
                           l2 = bf16_rn(f.z - bf16_tof(h2)), l3 = bf16_rn(f.w - bf16_tof(h3));
            const int idx = swz(br, bq * 8 + i * 2);
            *(uint2*)&BsHi[idx] = make_uint2((h1 << 16) | h0, (h3 << 16) | h2);
            *(uint2*)&BsLo[idx] = make_uint2((l1 << 16) | l0, (l3 << 16) | l2);
        }
        __syncthreads();

#pragma unroll
        for (int kk = 0; kk < 2; ++kk) {
            short8b ahh[4], alo[4], bhh[2], blo[2];
#pragma unroll
            for (int mi = 0; mi < 4; ++mi) {
                const int idx = swz(wm * 64 + mi * 16 + fr, kk * 16 + kg4 * 4);
                const uint4 th = *(const uint4*)&AsHi[idx];
                const uint4 tl = *(const uint4*)&AsLo[idx];
                ahh[mi] = *(const short8b*)&th;
                alo[mi] = *(const short8b*)&tl;
            }
#pragma unroll
            for (int ni = 0; ni < 2; ++ni) {
                const int idx = swz(wn * 32 + ni * 16 + fr, kk * 16 + kg4 * 4);
                const uint4 th = *(const uint4*)&BsHi[idx];
                const uint4 tl = *(const uint4*)&BsLo[idx];
                bhh[ni] = *(const short8b*)&th;
                blo[ni] = *(const short8b*)&tl;
            }
#pragma unroll
            for (int mi = 0; mi < 4; ++mi)
#pragma unroll
                for (int ni = 0; ni < 2; ++ni) {
                    acc[mi][ni] = __builtin_amdgcn_mfma_f32_16x16x32_bf16(ahh[mi], bhh[ni], acc[mi][ni], 0, 0, 0);
                    acc[mi][ni] = __builtin_amdgcn_mfma_f32_16x16x32_bf16(ahh[mi], blo[ni], acc[mi][ni], 0, 0, 0);
                    acc[mi][ni] = __builtin_amdgcn_mfma_f32_16x16x32_bf16(alo[mi], bhh[ni], acc[mi][ni], 0, 0, 0);
                }
        }
        __syncthreads();
    }

    // epilogue: C/D layout col=lane&15, row=(lane>>4)*4+reg  [m89-verified]
#pragma unroll
    for (int ni = 0; ni < 2; ++ni) {
        const int e = bn * GBN + wn * 32 + ni * 16 + fr;
        const float bv = bias[e];
#pragma unroll
        for (int mi = 0; mi < 4; ++mi) {
            const int mbase = bm * GBM + wm * 64 + mi * 16 + kg4 * 4;
#pragma unroll
            for (int r = 0; r < 4; ++r)
                out[(size_t)(mbase + r) * EDIM + e] = acc[mi][ni][r] + bv;
        }
    }
}

// ---------------- launcher ----------------
extern "C" void kernel_launch(void* const* d_in, const int* in_sizes, int n_in,
                              void* d_out, int out_size, void* d_ws, size_t ws_size,
                              hipStream_t stream) {
    const float* img      = (const float*)d_in[0];
    const int*   segments = (const int*)d_in[1];
    const float* proj_w   = (const float*)d_in[2];
    const float* proj_b   = (const float*)d_in[3];
    float* out = (float*)d_out;

    uint32_t* apk = (uint32_t*)d_ws;
    int*      cnt = (int*)((char*)d_ws + APK_BYTES);

    // zero packed feature buffer (u32 0 == two bf16 zeros); ws is re-poisoned each call
    hipMemsetAsync(apk, 0, APK_BYTES, stream);

    hist_kernel<<<BATCH * NCHUNK, 256, 0, stream>>>(segments, cnt);
    scan_kernel<<<MROWS / 256, 256, 0, stream>>>(cnt);
    scatter_kernel<<<BATCH * NCHUNK, 256, 0, stream>>>(img, segments, cnt, apk);

    dim3 grid(MROWS / GBM, EDIM / GBN);
    gemm_kernel<<<grid, 256, 0, stream>>>(apk, proj_w, proj_b, out);
}

// Round 7
// 288.342 us; speedup vs baseline: 1.8174x; 1.3991x over previous
//
#include <hip/hip_runtime.h>
#include <hip/hip_bf16.h>
#include <cstdint>

// Problem constants (fixed by reference)
#define BATCH 32
#define NCH 3
#define HW 147456            // 384*384
#define NSEG 256
#define NPIX 400
#define KDIM 1200            // NCH*NPIX
#define K_STORE 1200         // A row stride in u32
#define K_LOOP 1216          // BK=64 * 19 iterations; tail [1200,1216) zero-guarded
#define EDIM 768
#define MROWS (BATCH * NSEG) // 8192

#define CHUNK 4096
#define NCHUNK (HW / CHUNK)  // 36
#define SUB 1024             // per-wave sub-chunk (4 waves/block)

#define APK_BYTES ((size_t)MROWS * K_STORE * 4)  // 39,321,600

typedef __attribute__((ext_vector_type(8))) short short8b; // 8 bf16
typedef __attribute__((ext_vector_type(4))) float f32x4;

// ---- split-bf16 helpers: v ≈ hi + lo, each bf16 (RN) ----
__device__ inline uint32_t bf16_rn(float f) {
    uint32_t u = __float_as_uint(f);
    return (u + 0x7fffu + ((u >> 16) & 1u)) >> 16;
}
__device__ inline float bf16_tof(uint32_t h) { return __uint_as_float(h << 16); }
__device__ inline uint32_t pack_split(float v) {
    uint32_t hi = bf16_rn(v);
    uint32_t lo = bf16_rn(v - bf16_tof(hi));
    return (lo << 16) | hi;
}

// ---------------- Phase 1a: per-chunk histograms ----------------
__global__ __launch_bounds__(256) void hist_kernel(const int* __restrict__ seg,
                                                   int* __restrict__ cnt) {
    __shared__ int h[NSEG];
    const int tid = threadIdx.x;
    h[tid] = 0;
    __syncthreads();
    const int blk = blockIdx.x;
    const int b = blk / NCHUNK, ck = blk % NCHUNK;
    const int* segb = seg + (size_t)b * HW + ck * CHUNK;
#pragma unroll
    for (int i = 0; i < CHUNK / 256; ++i) atomicAdd(&h[segb[i * 256 + tid]], 1);
    __syncthreads();
    cnt[blk * NSEG + tid] = h[tid];
}

// ---------------- Phase 1b: exclusive scan over chunks per (b, s) ----------------
__global__ __launch_bounds__(256) void scan_kernel(int* __restrict__ cnt) {
    const int t = blockIdx.x * 256 + threadIdx.x;
    const int b = t >> 8, s = t & 255;
    int run = 0;
#pragma unroll
    for (int ck = 0; ck < NCHUNK; ++ck) {
        int* p = cnt + ((size_t)(b * NCHUNK + ck)) * NSEG + s;
        int v = *p;
        *p = run;
        run += v;
    }
}

// ---------------- Phase 1c: scatter v3 — LDS segment-sort, coalesced writeout ----------------
// 4 waves/block, each owning a sequential 1024-pixel sub-chunk (stability).
// pass1: ballot counts -> cursors; chunk-local exclusive prefix (lb).
// pass2: stage packed split-bf16 pixels into LDS slot j = lb[s] + local_rank.
// writeout: linear j, binary-search owning segment -> runs of consecutive
// addresses per (seg,chan) => wave-coalesced global stores.
// ck==35 block additionally zeroes each segment's tail [total,400) (no memset).
__global__ __launch_bounds__(256) void scatter_kernel(const float* __restrict__ img,
                                                      const int* __restrict__ seg,
                                                      const int* __restrict__ base,
                                                      uint32_t* __restrict__ apk) {
    __shared__ int sbase[NSEG];        // this chunk's global base per seg
    __shared__ int wpos[4][NSEG];      // counts -> per-wave cursors
    __shared__ int lb[NSEG];           // chunk-local exclusive prefix
    __shared__ uint32_t st0[CHUNK], st1[CHUNK], st2[CHUNK]; // 48 KB staging

    const int tid = threadIdx.x;
    const int lane = tid & 63;
    const int wid = tid >> 6;
    const int blk = blockIdx.x;
    const int b = blk / NCHUNK, ck = blk % NCHUNK;

    sbase[tid] = base[(size_t)blk * NSEG + tid];
    wpos[0][tid] = 0; wpos[1][tid] = 0; wpos[2][tid] = 0; wpos[3][tid] = 0;
    __syncthreads();

    const int* segb = seg + (size_t)b * HW;
    const float* imgb = img + (size_t)b * NCH * HW;
    const int startp = ck * CHUNK + wid * SUB;
    const unsigned long long lt = (lane == 0) ? 0ull : ((~0ull) >> (64 - lane));

    int sv[16];
    unsigned long long mv[16];
    // pass 1: per-wave per-segment counts
#pragma unroll
    for (int g = 0; g < 16; ++g) {
        const int p = startp + g * 64 + lane;
        const int s = segb[p];
        unsigned long long m = ~0ull;
#pragma unroll
        for (int bit = 0; bit < 8; ++bit) {
            unsigned long long bal = __ballot((s >> bit) & 1);
            m &= ((s >> bit) & 1) ? bal : ~bal;
        }
        sv[g] = s; mv[g] = m;
        if ((m & lt) == 0ull) atomicAdd(&wpos[wid][s], __popcll(m));
    }
    __syncthreads();

    // counts -> per-wave global cursors; chunk count per seg
    int csum;
    {
        const int s = tid;
        int r = sbase[s];
        int t0 = wpos[0][s]; wpos[0][s] = r; r += t0;
        int t1 = wpos[1][s]; wpos[1][s] = r; r += t1;
        int t2 = wpos[2][s]; wpos[2][s] = r; r += t2;
        int t3 = wpos[3][s]; wpos[3][s] = r; r += t3;
        csum = r - sbase[s];
        lb[s] = csum;
    }
    __syncthreads();
    // inclusive Hillis-Steele scan of lb, then convert to exclusive
#pragma unroll
    for (int off = 1; off < NSEG; off <<= 1) {
        int y = (tid >= off) ? lb[tid - off] : 0;
        __syncthreads();
        lb[tid] += y;
        __syncthreads();
    }
    {
        const int excl = lb[tid] - csum;
        __syncthreads();
        lb[tid] = excl;
    }
    __syncthreads();

    // pass 2: assign ranks (stable), stage into LDS at chunk-sorted slot j
#pragma unroll
    for (int g = 0; g < 16; ++g) {
        const int p = startp + g * 64 + lane;
        const int s = sv[g];
        const unsigned long long m = mv[g];
        const int rig = __popcll(m & lt);
        const int leader = __ffsll((unsigned long long)m) - 1;
        int old = 0;
        if (rig == 0) old = atomicAdd(&wpos[wid][s], __popcll(m));
        old = __shfl(old, leader, 64);
        const int rank = old + rig;                 // global rank in segment
        const int j = lb[s] + (rank - sbase[s]);    // chunk-local sorted slot
        st0[j] = pack_split(imgb[p]);
        st1[j] = pack_split(imgb[HW + p]);
        st2[j] = pack_split(imgb[2 * HW + p]);
    }
    __syncthreads();

    // writeout: linear over sorted slots; coalesced runs per (seg,chan)
    uint32_t* apkb = apk + (size_t)b * NSEG * K_STORE;
#pragma unroll
    for (int it = 0; it < CHUNK / 256; ++it) {
        const int j = it * 256 + tid;
        // last s with lb[s] <= j  (lb sorted non-decreasing, lb[0]=0)
        int s = 0;
#pragma unroll
        for (int step = 128; step; step >>= 1) {
            const int c = s + step;
            if (c < NSEG && lb[c] <= j) s = c;
        }
        const int rank = sbase[s] + (j - lb[s]);
        if (rank < NPIX) {
            uint32_t* dst = apkb + (size_t)s * K_STORE + rank;
            dst[0]        = st0[j];
            dst[NPIX]     = st1[j];
            dst[2 * NPIX] = st2[j];
        }
    }

    // tail zero (replaces 39 MB memset): only the last chunk knows grand totals
    if (ck == NCHUNK - 1) {
        __syncthreads();
        const int tot = wpos[3][tid];  // = grand total for segment tid
        uint32_t* row = apkb + (size_t)tid * K_STORE;
        for (int r2 = tot; r2 < NPIX; ++r2) {
            row[r2] = 0u; row[NPIX + r2] = 0u; row[2 * NPIX + r2] = 0u;
        }
    }
}

// ---------------- Phase 2: split-bf16 MFMA GEMM (round-5 verified) ----------------
#define GBM 128
#define GBN 64
#define BKG 64
#define LDSW 32  // dwords per LDS row (64 bf16)

__device__ inline int swz(int r, int c) { return r * LDSW + (c ^ ((r & 7) << 2)); }

__global__ __launch_bounds__(256) void gemm_kernel(const uint32_t* __restrict__ apk,
                                                   const float* __restrict__ W,
                                                   const float* __restrict__ bias,
                                                   float* __restrict__ out) {
    __shared__ uint32_t AsHi[GBM * LDSW], AsLo[GBM * LDSW];
    __shared__ uint32_t BsHi[GBN * LDSW], BsLo[GBN * LDSW];

    const int tid = threadIdx.x;
    const int lane = tid & 63;
    const int wid = tid >> 6;
    const int wm = wid >> 1, wn = wid & 1;
    const int fr = lane & 15, kg4 = lane >> 4;
    const int bm = blockIdx.x, bn = blockIdx.y;

    const int ar = tid >> 1, ah = tid & 1;   // A-stage: 2 thr/row, 32 u32 each
    const int br = tid >> 2, bq = tid & 3;   // B-stage: 4 thr/row, 16 f32 each
    const uint32_t* arow0 = apk + (size_t)(bm * GBM + ar) * K_STORE;
    const float* wrow0 = W + (size_t)(bn * GBN + br) * KDIM;

    f32x4 acc[4][2] = {};

    for (int k0 = 0; k0 < K_LOOP; k0 += BKG) {
        // ---- stage A: packed u32 -> hi/lo bf16 LDS tiles (swizzled), K-tail zeroed ----
#pragma unroll
        for (int i = 0; i < 8; ++i) {
            const int kA = k0 + ah * 32 + i * 4;
            uint4 p = make_uint4(0u, 0u, 0u, 0u);
            if (kA < KDIM) p = *(const uint4*)(arow0 + kA);
            const uint32_t h0 = (p.y << 16) | (p.x & 0xffffu);
            const uint32_t l0 = (p.y & 0xffff0000u) | (p.x >> 16);
            const uint32_t h1 = (p.w << 16) | (p.z & 0xffffu);
            const uint32_t l1 = (p.w & 0xffff0000u) | (p.z >> 16);
            const int idx = swz(ar, ah * 16 + i * 2);
            *(uint2*)&AsHi[idx] = make_uint2(h0, h1);
            *(uint2*)&AsLo[idx] = make_uint2(l0, l1);
        }
        // ---- stage B: f32 W -> hi/lo bf16 (K-tail zeroed) ----
#pragma unroll
        for (int i = 0; i < 4; ++i) {
            const int kB = k0 + bq * 16 + i * 4;
            float4 f = make_float4(0.f, 0.f, 0.f, 0.f);
            if (kB < KDIM) f = *(const float4*)(wrow0 + kB);
            const uint32_t h0 = bf16_rn(f.x), h1 = bf16_rn(f.y),
                           h2 = bf16_rn(f.z), h3 = bf16_rn(f.w);
            const uint32_t l0 = bf16_rn(f.x - bf16_tof(h0)), l1 = bf16_rn(f.y - bf16_tof(h1)),
                           l2 = bf16_rn(f.z - bf16_tof(h2)), l3 = bf16_rn(f.w - bf16_tof(h3));
            const int idx = swz(br, bq * 8 + i * 2);
            *(uint2*)&BsHi[idx] = make_uint2((h1 << 16) | h0, (h3 << 16) | h2);
            *(uint2*)&BsLo[idx] = make_uint2((l1 << 16) | l0, (l3 << 16) | l2);
        }
        __syncthreads();

#pragma unroll
        for (int kk = 0; kk < 2; ++kk) {
            short8b ahh[4], alo[4], bhh[2], blo[2];
#pragma unroll
            for (int mi = 0; mi < 4; ++mi) {
                const int idx = swz(wm * 64 + mi * 16 + fr, kk * 16 + kg4 * 4);
                const uint4 th = *(const uint4*)&AsHi[idx];
                const uint4 tl = *(const uint4*)&AsLo[idx];
                ahh[mi] = *(const short8b*)&th;
                alo[mi] = *(const short8b*)&tl;
            }
#pragma unroll
            for (int ni = 0; ni < 2; ++ni) {
                const int idx = swz(wn * 32 + ni * 16 + fr, kk * 16 + kg4 * 4);
                const uint4 th = *(const uint4*)&BsHi[idx];
                const uint4 tl = *(const uint4*)&BsLo[idx];
                bhh[ni] = *(const short8b*)&th;
                blo[ni] = *(const short8b*)&tl;
            }
#pragma unroll
            for (int mi = 0; mi < 4; ++mi)
#pragma unroll
                for (int ni = 0; ni < 2; ++ni) {
                    acc[mi][ni] = __builtin_amdgcn_mfma_f32_16x16x32_bf16(ahh[mi], bhh[ni], acc[mi][ni], 0, 0, 0);
                    acc[mi][ni] = __builtin_amdgcn_mfma_f32_16x16x32_bf16(ahh[mi], blo[ni], acc[mi][ni], 0, 0, 0);
                    acc[mi][ni] = __builtin_amdgcn_mfma_f32_16x16x32_bf16(alo[mi], bhh[ni], acc[mi][ni], 0, 0, 0);
                }
        }
        __syncthreads();
    }

    // epilogue: C/D layout col=lane&15, row=(lane>>4)*4+reg  [m89-verified]
#pragma unroll
    for (int ni = 0; ni < 2; ++ni) {
        const int e = bn * GBN + wn * 32 + ni * 16 + fr;
        const float bv = bias[e];
#pragma unroll
        for (int mi = 0; mi < 4; ++mi) {
            const int mbase = bm * GBM + wm * 64 + mi * 16 + kg4 * 4;
#pragma unroll
            for (int r = 0; r < 4; ++r)
                out[(size_t)(mbase + r) * EDIM + e] = acc[mi][ni][r] + bv;
        }
    }
}

// ---------------- launcher ----------------
extern "C" void kernel_launch(void* const* d_in, const int* in_sizes, int n_in,
                              void* d_out, int out_size, void* d_ws, size_t ws_size,
                              hipStream_t stream) {
    const float* img      = (const float*)d_in[0];
    const int*   segments = (const int*)d_in[1];
    const float* proj_w   = (const float*)d_in[2];
    const float* proj_b   = (const float*)d_in[3];
    float* out = (float*)d_out;

    uint32_t* apk = (uint32_t*)d_ws;
    int*      cnt = (int*)((char*)d_ws + APK_BYTES);

    // no memset: scatter writes every (seg, rank<total) slot; ck==35 blocks
    // zero each segment's tail [total, 400) per channel.

    hist_kernel<<<BATCH * NCHUNK, 256, 0, stream>>>(segments, cnt);
    scan_kernel<<<MROWS / 256, 256, 0, stream>>>(cnt);
    scatter_kernel<<<BATCH * NCHUNK, 256, 0, stream>>>(img, segments, cnt, apk);

    dim3 grid(MROWS / GBM, EDIM / GBN);
    gemm_kernel<<<grid, 256, 0, stream>>>(apk, proj_w, proj_b, out);
}

// Round 8
// 260.873 us; speedup vs baseline: 2.0088x; 1.1053x over previous
//
#include <hip/hip_runtime.h>
#include <hip/hip_bf16.h>
#include <cstdint>

// Problem constants (fixed by reference)
#define BATCH 32
#define NCH 3
#define HW 147456            // 384*384
#define NSEG 256
#define NPIX 400
#define KDIM 1200            // NCH*NPIX
#define EDIM 768
#define MROWS (BATCH * NSEG) // 8192

#define CHUNK 4096
#define NCHUNK (HW / CHUNK)  // 36
#define SUB 1024             // per-wave sub-chunk (4 waves/block)

#define ROW_BYTES 4800       // per (b,seg) row: packed u32[1200] OR planes [hi 2400B | lo 2400B]
#define APK_BYTES ((size_t)MROWS * ROW_BYTES)  // 39,321,600 (proven ws footprint)
#define W_BYTES (EDIM * KDIM * 4)              // 3,686,400

typedef __attribute__((ext_vector_type(8))) short short8b;   // 8 bf16
typedef __attribute__((ext_vector_type(16))) float f32x16;

// ---- split-bf16 helpers: v ~= hi + lo, each bf16 (RN) ----
__device__ __forceinline__ uint32_t bf16_rn(float f) {
    uint32_t u = __float_as_uint(f);
    return (u + 0x7fffu + ((u >> 16) & 1u)) >> 16;
}
__device__ __forceinline__ float bf16_tof(uint32_t h) { return __uint_as_float(h << 16); }
__device__ __forceinline__ uint32_t pack_split(float v) {
    uint32_t hi = bf16_rn(v);
    uint32_t lo = bf16_rn(v - bf16_tof(hi));
    return (lo << 16) | hi;
}

// async global->LDS, 16B per lane; LDS dest = uniform base + lane*16 (m104);
// swizzling is done on the per-lane GLOBAL source address (m173 pattern)
__device__ __forceinline__ void async_copy16(const void* gsrc, void* ldst) {
    __builtin_amdgcn_global_load_lds(
        (const __attribute__((address_space(1))) uint32_t*)gsrc,
        (__attribute__((address_space(3))) uint32_t*)ldst, 16, 0, 0);
}

// ---------------- Phase 1a: per-chunk histograms ----------------
__global__ __launch_bounds__(256) void hist_kernel(const int* __restrict__ seg,
                                                   int* __restrict__ cnt) {
    __shared__ int h[NSEG];
    const int tid = threadIdx.x;
    h[tid] = 0;
    __syncthreads();
    const int blk = blockIdx.x;
    const int b = blk / NCHUNK, ck = blk % NCHUNK;
    const int* segb = seg + (size_t)b * HW + ck * CHUNK;
#pragma unroll
    for (int i = 0; i < CHUNK / 256; ++i) atomicAdd(&h[segb[i * 256 + tid]], 1);
    __syncthreads();
    cnt[blk * NSEG + tid] = h[tid];
}

// ---------------- Phase 1b: exclusive scan over chunks per (b, s) ----------------
// After the loop, the grand total is stored into the chunk-0 slot (whose base is
// always 0 and is special-cased in scatter). repackA reads it for tail-zeroing.
__global__ __launch_bounds__(256) void scan_kernel(int* __restrict__ cnt) {
    const int t = blockIdx.x * 256 + threadIdx.x;
    const int b = t >> 8, s = t & 255;
    int run = 0;
#pragma unroll
    for (int ck = 0; ck < NCHUNK; ++ck) {
        int* p = cnt + ((size_t)(b * NCHUNK + ck)) * NSEG + s;
        int v = *p;
        *p = run;
        run += v;
    }
    cnt[(size_t)(b * NCHUNK) * NSEG + s] = run;   // grand total (chunk-0 base == 0)
}

// ---------------- Phase 1c: scatter v4 — LDS segment-sort, coalesced writeout ----------------
// v3 + : sbase/lb packed into one word ((sb<<13)|lb) -> 53KB LDS -> 3 blocks/CU;
// ck==0 base is the constant 0 (slot holds grand total now); tail-zero moved to repackA.
__global__ __launch_bounds__(256) void scatter_kernel(const float* __restrict__ img,
                                                      const int* __restrict__ seg,
                                                      const int* __restrict__ base,
                                                      uint32_t* __restrict__ apk) {
    __shared__ int wpos[4][NSEG];      // counts -> per-wave cursors
    __shared__ int sl[NSEG];           // scan scratch -> packed (sbase<<13)|lb
    __shared__ uint32_t st0[CHUNK], st1[CHUNK], st2[CHUNK]; // 48 KB staging

    const int tid = threadIdx.x;
    const int lane = tid & 63;
    const int wid = tid >> 6;
    const int blk = blockIdx.x;
    const int b = blk / NCHUNK, ck = blk % NCHUNK;

    const int sb = (ck == 0) ? 0 : base[(size_t)blk * NSEG + tid];  // this chunk's base for seg 'tid'
    wpos[0][tid] = 0; wpos[1][tid] = 0; wpos[2][tid] = 0; wpos[3][tid] = 0;
    __syncthreads();

    const int* segb = seg + (size_t)b * HW;
    const float* imgb = img + (size_t)b * NCH * HW;
    const int startp = ck * CHUNK + wid * SUB;
    const unsigned long long lt = (lane == 0) ? 0ull : ((~0ull) >> (64 - lane));

    int sv[16];
    unsigned long long mv[16];
    // pass 1: per-wave per-segment counts (stable: waves own disjoint sequential ranges)
#pragma unroll
    for (int g = 0; g < 16; ++g) {
        const int p = startp + g * 64 + lane;
        const int s = segb[p];
        unsigned long long m = ~0ull;
#pragma unroll
        for (int bit = 0; bit < 8; ++bit) {
            unsigned long long bal = __ballot((s >> bit) & 1);
            m &= ((s >> bit) & 1) ? bal : ~bal;
        }
        sv[g] = s; mv[g] = m;
        if ((m & lt) == 0ull) atomicAdd(&wpos[wid][s], __popcll(m));
    }
    __syncthreads();

    // counts -> per-wave global cursors; chunk count per seg into sl
    int csum;
    {
        const int s = tid;
        int r = sb;
        int t0 = wpos[0][s]; wpos[0][s] = r; r += t0;
        int t1 = wpos[1][s]; wpos[1][s] = r; r += t1;
        int t2 = wpos[2][s]; wpos[2][s] = r; r += t2;
        int t3 = wpos[3][s]; wpos[3][s] = r; r += t3;
        csum = r - sb;
        sl[s] = csum;
    }
    __syncthreads();
    // inclusive Hillis-Steele scan, then pack exclusive prefix with sbase
#pragma unroll
    for (int off = 1; off < NSEG; off <<= 1) {
        int y = (tid >= off) ? sl[tid - off] : 0;
        __syncthreads();
        sl[tid] += y;
        __syncthreads();
    }
    {
        const int excl = sl[tid] - csum;
        __syncthreads();
        sl[tid] = (sb << 13) | excl;   // sb < 2^18, excl <= 4096 < 2^13
    }
    __syncthreads();

    // pass 2: assign ranks (stable), stage into LDS at chunk-sorted slot j
#pragma unroll
    for (int g = 0; g < 16; ++g) {
        const int p = startp + g * 64 + lane;
        const int s = sv[g];
        const unsigned long long m = mv[g];
        const int rig = __popcll(m & lt);
        const int leader = __ffsll((unsigned long long)m) - 1;
        int old = 0;
        if (rig == 0) old = atomicAdd(&wpos[wid][s], __popcll(m));
        old = __shfl(old, leader, 64);
        const int rank = old + rig;                 // global rank in segment
        const int v = sl[s];
        const int j = rank - (v >> 13) + (v & 8191); // chunk-local sorted slot
        st0[j] = pack_split(imgb[p]);
        st1[j] = pack_split(imgb[HW + p]);
        st2[j] = pack_split(imgb[2 * HW + p]);
    }
    __syncthreads();

    // writeout: linear over sorted slots; coalesced runs per (seg,chan)
    uint32_t* apkb = apk + (size_t)b * NSEG * (ROW_BYTES / 4);
#pragma unroll
    for (int it = 0; it < CHUNK / 256; ++it) {
        const int j = it * 256 + tid;
        // last s with lb[s] <= j  (lb non-decreasing, lb[0]=0)
        int s = 0;
#pragma unroll
        for (int step = 128; step; step >>= 1) {
            const int c = s + step;
            if (c < NSEG && (sl[c] & 8191) <= j) s = c;
        }
        const int v = sl[s];
        const int rank = (v >> 13) + (j - (v & 8191));
        if (rank < NPIX) {
            uint32_t* dst = apkb + (size_t)s * (ROW_BYTES / 4) + rank;
            dst[0]            = st0[j];
            dst[NPIX]         = st1[j];
            dst[2 * NPIX]     = st2[j];
        }
    }
}

// ---------------- Phase 1d: repack A rows in place: packed u32 -> [hi|lo] bf16 planes ----------------
// One wave per (b,seg) row. Also zeroes tail ranks [tot,400) per channel (replaces memset).
__global__ __launch_bounds__(256) void repackA_kernel(uint32_t* __restrict__ apk,
                                                      const int* __restrict__ cnt) {
    __shared__ uint32_t buf[4][KDIM];
    const int tid = threadIdx.x;
    const int l = tid & 63;
    const int wid = tid >> 6;
    const int row = blockIdx.x * 4 + wid;   // 0..8191
    const int b = row >> 8, s = row & 255;
    int tot = cnt[(size_t)(b * NCHUNK) * NSEG + s];
    if (tot > NPIX) tot = NPIX;

    uint32_t* rowp = apk + (size_t)row * (ROW_BYTES / 4);
#pragma unroll
    for (int i = 0; i < 19; ++i) {
        const int idx = i * 64 + l;
        if (idx < KDIM) buf[wid][idx] = rowp[idx];
    }
    __syncthreads();
#pragma unroll
    for (int i = 0; i < 10; ++i) {
        const int j = i * 64 + l;               // hi/lo u32 index, 0..599
        if (j < KDIM / 2) {
            const int k0 = 2 * j, k1 = 2 * j + 1;
            const int r0 = k0 - ((k0 * 41) >> 14) * 400;   // rank within channel
            const int r1 = k1 - ((k1 * 41) >> 14) * 400;
            const uint32_t p0 = (r0 < tot) ? buf[wid][k0] : 0u;
            const uint32_t p1 = (r1 < tot) ? buf[wid][k1] : 0u;
            rowp[j]             = (p0 & 0xffffu) | (p1 << 16);          // hi plane
            rowp[KDIM / 2 + j]  = (p0 >> 16) | (p1 & 0xffff0000u);      // lo plane
        }
    }
}

// ---------------- Phase 1e: repack W in place: f32 -> [hi|lo] bf16 planes ----------------
// Safe: harness restores d_in from pristine before every launch; same work each call.
__global__ __launch_bounds__(256) void repackW_kernel(float* __restrict__ w) {
    __shared__ float buf[4][KDIM];
    const int tid = threadIdx.x;
    const int l = tid & 63;
    const int wid = tid >> 6;
    const int row = blockIdx.x * 4 + wid;   // 0..767
    float* rowp = w + (size_t)row * KDIM;
#pragma unroll
    for (int i = 0; i < 19; ++i) {
        const int idx = i * 64 + l;
        if (idx < KDIM) buf[wid][idx] = rowp[idx];
    }
    __syncthreads();
    uint32_t* rowu = (uint32_t*)rowp;
#pragma unroll
    for (int i = 0; i < 10; ++i) {
        const int j = i * 64 + l;
        if (j < KDIM / 2) {
            const float f0 = buf[wid][2 * j], f1 = buf[wid][2 * j + 1];
            const uint32_t h0 = bf16_rn(f0), h1 = bf16_rn(f1);
            const uint32_t l0 = bf16_rn(f0 - bf16_tof(h0));
            const uint32_t l1 = bf16_rn(f1 - bf16_tof(h1));
            rowu[j]            = h0 | (h1 << 16);   // hi plane
            rowu[KDIM / 2 + j] = l0 | (l1 << 16);   // lo plane
        }
    }
}

// ---------------- Phase 2: GEMM v3 — 32x32x16 MFMA, global_load_lds staging ----------------
// Block 128x64 (2 waves, each 64x64 = 2x2 of 32x32). BK=64. LDS 48KB -> 3 blocks/CU.
// A and W are [hi 2400B | lo 2400B] bf16 planes per 4800B row. Staging uses
// pre-swizzled global source (XOR (row&7)<<4 within 128B window); frag reads use same XOR.
__global__ __launch_bounds__(128) void gemm_kernel(const uint8_t* __restrict__ A,
                                                   const uint8_t* __restrict__ Wp,
                                                   const float* __restrict__ bias,
                                                   float* __restrict__ out) {
    __shared__ uint8_t smem[49152];  // AsHi 16K | AsLo 16K | BsHi 8K | BsLo 8K

    const int tid = threadIdx.x;
    const int l = tid & 63;
    const int wid = tid >> 6;

    // XCD-grouped decode: all 12 bn-blocks of a bm group land on one XCD (bid%8)
    const int bid = blockIdx.x;
    const int xcd = bid & 7;
    const int t = bid >> 3;
    const int bn = t % 12;
    const int bm = (t / 12) * 8 + xcd;

    const int swzl = ((l & 7) * 16) ^ ((l >> 3) << 4);  // per-lane swizzled source byte
    const int xread = (l & 7) << 4;                     // frag-read XOR ( == (row&7)<<4 )

    const uint8_t* Abase = A + (size_t)bm * 128 * ROW_BYTES;

    f32x16 acc[2][2] = {};

    for (int k0 = 0; k0 < KDIM; k0 += 64) {
        // ---- stage A hi+lo: 32KB, 16B/lane async ----
#pragma unroll
        for (int ii = 0; ii < 8; ++ii) {
            const int i = wid * 8 + ii;               // 0..15
            const int row = i * 8 + (l >> 3);         // 0..127 (row&7 == l>>3)
            const size_t gb = (size_t)row * ROW_BYTES + k0 * 2 + swzl;
            async_copy16(Abase + gb,        smem + i * 1024);           // hi
            async_copy16(Abase + gb + 2400, smem + 16384 + i * 1024);   // lo
        }
        // ---- stage B hi+lo: 16KB ----
#pragma unroll
        for (int ii = 0; ii < 4; ++ii) {
            const int i = wid * 4 + ii;               // 0..7
            const int row = i * 8 + (l >> 3);         // 0..63
            const size_t gb = (size_t)(bn * 64 + row) * ROW_BYTES + k0 * 2 + swzl;
            async_copy16(Wp + gb, smem + 32768 + i * 1024);             // hi
            size_t gl = gb + 2400;
            if (gl + 16 > (size_t)W_BYTES) gl = 0;    // last-row lo K-spill clamp (data unused)
            async_copy16(Wp + gl, smem + 40960 + i * 1024);             // lo
        }
        __syncthreads();

#pragma unroll
        for (int ks = 0; ks < 4; ++ks) {
            if (k0 + ks * 16 >= KDIM) break;          // K tail: skip garbage k>=1200
            const int koff = ks * 32 + ((l >> 5) * 16);
            short8b ahi[2], alo[2], bhi[2], blo[2];
#pragma unroll
            for (int mi = 0; mi < 2; ++mi) {
                const int row = wid * 64 + mi * 32 + (l & 31);   // row&7 == l&7
                const int byteA = row * 128 + (koff ^ xread);
                ahi[mi] = *(const short8b*)(smem + byteA);
                alo[mi] = *(const short8b*)(smem + 16384 + byteA);
            }
#pragma unroll
            for (int ni = 0; ni < 2; ++ni) {
                const int row = ni * 32 + (l & 31);
                const int byteB = row * 128 + (koff ^ xread);
                bhi[ni] = *(const short8b*)(smem + 32768 + byteB);
                blo[ni] = *(const short8b*)(smem + 40960 + byteB);
            }
#pragma unroll
            for (int mi = 0; mi < 2; ++mi)
#pragma unroll
                for (int ni = 0; ni < 2; ++ni) {
                    acc[mi][ni] = __builtin_amdgcn_mfma_f32_32x32x16_bf16(ahi[mi], bhi[ni], acc[mi][ni], 0, 0, 0);
                    acc[mi][ni] = __builtin_amdgcn_mfma_f32_32x32x16_bf16(ahi[mi], blo[ni], acc[mi][ni], 0, 0, 0);
                    acc[mi][ni] = __builtin_amdgcn_mfma_f32_32x32x16_bf16(alo[mi], bhi[ni], acc[mi][ni], 0, 0, 0);
                }
        }
        __syncthreads();
    }

    // epilogue: 32x32 C/D layout col=lane&31, row=(reg&3)+8*(reg>>2)+4*(lane>>5) [m74/m101]
#pragma unroll
    for (int ni = 0; ni < 2; ++ni) {
        const int e = bn * 64 + ni * 32 + (l & 31);
        const float bv = bias[e];
#pragma unroll
        for (int mi = 0; mi < 2; ++mi) {
            const int rbase = bm * 128 + wid * 64 + mi * 32 + 4 * (l >> 5);
#pragma unroll
            for (int r = 0; r < 16; ++r) {
                const int row = rbase + (r & 3) + 8 * (r >> 2);
                out[(size_t)row * EDIM + e] = acc[mi][ni][r] + bv;
            }
        }
    }
}

// ---------------- launcher ----------------
extern "C" void kernel_launch(void* const* d_in, const int* in_sizes, int n_in,
                              void* d_out, int out_size, void* d_ws, size_t ws_size,
                              hipStream_t stream) {
    const float* img      = (const float*)d_in[0];
    const int*   segments = (const int*)d_in[1];
    float*       proj_w   = (float*)d_in[2];        // repacked in place each launch
    const float* proj_b   = (const float*)d_in[3];
    float* out = (float*)d_out;

    uint32_t* apk = (uint32_t*)d_ws;
    int*      cnt = (int*)((char*)d_ws + APK_BYTES);

    hist_kernel<<<BATCH * NCHUNK, 256, 0, stream>>>(segments, cnt);
    scan_kernel<<<MROWS / 256, 256, 0, stream>>>(cnt);
    repackW_kernel<<<EDIM / 4, 256, 0, stream>>>(proj_w);
    scatter_kernel<<<BATCH * NCHUNK, 256, 0, stream>>>(img, segments, cnt, apk);
    repackA_kernel<<<MROWS / 4, 256, 0, stream>>>(apk, cnt);

    gemm_kernel<<<64 * 12, 128, 0, stream>>>((const uint8_t*)apk, (const uint8_t*)proj_w,
                                             proj_b, out);
}

// Round 9
// 224.754 us; speedup vs baseline: 2.3316x; 1.1607x over previous
//
#include <hip/hip_runtime.h>
#include <hip/hip_bf16.h>
#include <cstdint>

// Problem constants (fixed by reference)
#define BATCH 32
#define NCH 3
#define HW 147456            // 384*384
#define NSEG 256
#define NPIX 400
#define KDIM 1200            // NCH*NPIX
#define EDIM 768
#define MROWS (BATCH * NSEG) // 8192

#define CHUNK 4096
#define NCHUNK (HW / CHUNK)  // 36
#define NW 8                 // scatter waves/block
#define SUBW (CHUNK / NW)    // 512 pixels per wave

#define ROW_BYTES 4800       // per (b,seg) row: [hi 2400B | lo 2400B] bf16 planes
#define APK_BYTES ((size_t)MROWS * ROW_BYTES)  // 39,321,600 (proven ws footprint)
#define W_BYTES (EDIM * KDIM * 4)              // 3,686,400

typedef __attribute__((ext_vector_type(8))) short short8b;   // 8 bf16
typedef __attribute__((ext_vector_type(16))) float f32x16;

// ---- split-bf16 helpers: v ~= hi + lo, each bf16 (RN) ----
__device__ __forceinline__ uint32_t bf16_rn(float f) {
    uint32_t u = __float_as_uint(f);
    return (u + 0x7fffu + ((u >> 16) & 1u)) >> 16;
}
__device__ __forceinline__ float bf16_tof(uint32_t h) { return __uint_as_float(h << 16); }
__device__ __forceinline__ uint32_t pack_split(float v) {
    uint32_t hi = bf16_rn(v);
    uint32_t lo = bf16_rn(v - bf16_tof(hi));
    return (lo << 16) | hi;
}

// async global->LDS, 16B/lane; LDS dest is wave-uniform base + lane*16 (m104);
// swizzle applied on per-lane GLOBAL source address (m173 pattern)
__device__ __forceinline__ void async_copy16(const void* gsrc, void* ldst) {
    __builtin_amdgcn_global_load_lds(
        (const __attribute__((address_space(1))) uint32_t*)gsrc,
        (__attribute__((address_space(3))) uint32_t*)ldst, 16, 0, 0);
}

// ---------------- Phase 1a: per-chunk histograms ----------------
__global__ __launch_bounds__(256) void hist_kernel(const int* __restrict__ seg,
                                                   int* __restrict__ cnt) {
    __shared__ int h[NSEG];
    const int tid = threadIdx.x;
    h[tid] = 0;
    __syncthreads();
    const int blk = blockIdx.x;
    const int b = blk / NCHUNK, ck = blk % NCHUNK;
    const int* segb = seg + (size_t)b * HW + ck * CHUNK;
#pragma unroll
    for (int i = 0; i < CHUNK / 256; ++i) atomicAdd(&h[segb[i * 256 + tid]], 1);
    __syncthreads();
    cnt[blk * NSEG + tid] = h[tid];
}

// ---------------- Phase 1b: exclusive scan over chunks per (b, s) ----------------
// Grand total is stored into the chunk-0 slot (base always 0, special-cased).
__global__ __launch_bounds__(256) void scan_kernel(int* __restrict__ cnt) {
    const int t = blockIdx.x * 256 + threadIdx.x;
    const int b = t >> 8, s = t & 255;
    int run = 0;
#pragma unroll
    for (int ck = 0; ck < NCHUNK; ++ck) {
        int* p = cnt + ((size_t)(b * NCHUNK + ck)) * NSEG + s;
        int v = *p;
        *p = run;
        run += v;
    }
    cnt[(size_t)(b * NCHUNK) * NSEG + s] = run;   // grand total
}

// ---------------- Phase 1c: scatter v5 — LDS sort + direct plane writeout ----------------
// 8 waves x 512-pixel sequential sub-chunks (stable). Writeout emits 6 u16
// stores per slot straight into the [hi|lo] bf16 plane layout (repackA fused).
__global__ __launch_bounds__(512) void scatter_kernel(const float* __restrict__ img,
                                                      const int* __restrict__ seg,
                                                      const int* __restrict__ base,
                                                      uint8_t* __restrict__ apk) {
    __shared__ int wpos[NW][NSEG];     // 8 KB: counts -> per-wave cursors
    __shared__ int sl[NSEG];           // packed (sbase<<13)|lb
    __shared__ uint32_t st0[CHUNK], st1[CHUNK], st2[CHUNK]; // 48 KB staging

    const int tid = threadIdx.x;
    const int lane = tid & 63;
    const int wid = tid >> 6;
    const int blk = blockIdx.x;
    const int b = blk / NCHUNK, ck = blk % NCHUNK;

    int sb = 0;
    if (tid < NSEG) sb = (ck == 0) ? 0 : base[(size_t)blk * NSEG + tid];
#pragma unroll
    for (int i = 0; i < (NW * NSEG) / 512; ++i) ((int*)wpos)[i * 512 + tid] = 0;
    __syncthreads();

    const int* segb = seg + (size_t)b * HW;
    const float* imgb = img + (size_t)b * NCH * HW;
    const int startp = ck * CHUNK + wid * SUBW;
    const unsigned long long lt = (lane == 0) ? 0ull : ((~0ull) >> (64 - lane));

    int sv[SUBW / 64];
    unsigned long long mv[SUBW / 64];
    // pass 1: per-wave per-segment counts (waves own disjoint sequential ranges)
#pragma unroll
    for (int g = 0; g < SUBW / 64; ++g) {
        const int p = startp + g * 64 + lane;
        const int s = segb[p];
        unsigned long long m = ~0ull;
#pragma unroll
        for (int bit = 0; bit < 8; ++bit) {
            unsigned long long bal = __ballot((s >> bit) & 1);
            m &= ((s >> bit) & 1) ? bal : ~bal;
        }
        sv[g] = s; mv[g] = m;
        if ((m & lt) == 0ull) atomicAdd(&wpos[wid][s], __popcll(m));
    }
    __syncthreads();

    // counts -> per-wave global cursors; chunk count per seg into sl
    int csum = 0;
    if (tid < NSEG) {
        int r = sb;
#pragma unroll
        for (int w = 0; w < NW; ++w) {
            const int t = wpos[w][tid];
            wpos[w][tid] = r;
            r += t;
        }
        csum = r - sb;
        sl[tid] = csum;
    }
    __syncthreads();
    // Hillis-Steele inclusive scan over 256 entries (threads >=256 idle at barriers)
#pragma unroll
    for (int off = 1; off < NSEG; off <<= 1) {
        int y = 0;
        if (tid < NSEG && tid >= off) y = sl[tid - off];
        __syncthreads();
        if (tid < NSEG) sl[tid] += y;
        __syncthreads();
    }
    {
        int excl = 0;
        if (tid < NSEG) excl = sl[tid] - csum;
        __syncthreads();
        if (tid < NSEG) sl[tid] = (sb << 13) | excl;  // sb<2^18, excl<=4096<2^13
    }
    __syncthreads();

    // pass 2: assign ranks (stable), stage packed split-bf16 at chunk-sorted slot j
#pragma unroll
    for (int g = 0; g < SUBW / 64; ++g) {
        const int p = startp + g * 64 + lane;
        const int s = sv[g];
        const unsigned long long m = mv[g];
        const int rig = __popcll(m & lt);
        const int leader = __ffsll((unsigned long long)m) - 1;
        int old = 0;
        if (rig == 0) old = atomicAdd(&wpos[wid][s], __popcll(m));
        old = __shfl(old, leader, 64);
        const int rank = old + rig;                  // global rank in segment
        const int v = sl[s];
        const int j = rank - (v >> 13) + (v & 8191); // chunk-local sorted slot
        st0[j] = pack_split(imgb[p]);
        st1[j] = pack_split(imgb[HW + p]);
        st2[j] = pack_split(imgb[2 * HW + p]);
    }
    __syncthreads();

    // writeout: linear slots; 6 contiguous u16 stores/slot into [hi|lo] planes
    uint8_t* apkb = apk + (size_t)b * NSEG * ROW_BYTES;
#pragma unroll
    for (int it = 0; it < CHUNK / 512; ++it) {
        const int j = it * 512 + tid;
        int s = 0;   // last s with lb[s] <= j
#pragma unroll
        for (int step = 128; step; step >>= 1) {
            const int c = s + step;
            if (c < NSEG && (sl[c] & 8191) <= j) s = c;
        }
        const int v = sl[s];
        const int rank = (v >> 13) + (j - (v & 8191));
        if (rank < NPIX) {
            uint16_t* hp = (uint16_t*)(apkb + (size_t)s * ROW_BYTES);
            uint16_t* lp = (uint16_t*)(apkb + (size_t)s * ROW_BYTES + 2400);
            const uint32_t v0 = st0[j], v1 = st1[j], v2 = st2[j];
            hp[rank]       = (uint16_t)v0;  lp[rank]       = (uint16_t)(v0 >> 16);
            hp[400 + rank] = (uint16_t)v1;  lp[400 + rank] = (uint16_t)(v1 >> 16);
            hp[800 + rank] = (uint16_t)v2;  lp[800 + rank] = (uint16_t)(v2 >> 16);
        }
    }
}

// ---------------- Phase 1d: tail-zero (rare: segments with < 400 pixels) ----------------
__global__ __launch_bounds__(256) void tailzero_kernel(uint8_t* __restrict__ apk,
                                                       const int* __restrict__ cnt) {
    const int tid = threadIdx.x;
    const int l = tid & 63;
    const int wid = tid >> 6;
    const int row = blockIdx.x * 4 + wid;   // 0..8191
    const int b = row >> 8, s = row & 255;
    const int tot = cnt[(size_t)(b * NCHUNK) * NSEG + s];
    if (tot >= NPIX) return;                // wave-uniform
    uint16_t* hp = (uint16_t*)(apk + (size_t)row * ROW_BYTES);
    uint16_t* lp = (uint16_t*)(apk + (size_t)row * ROW_BYTES + 2400);
    for (int r = tot + l; r < NPIX; r += 64) {
        hp[r] = 0; lp[r] = 0;
        hp[400 + r] = 0; lp[400 + r] = 0;
        hp[800 + r] = 0; lp[800 + r] = 0;
    }
}

// ---------------- Phase 1e: repack W in place: f32 -> [hi|lo] bf16 planes ----------------
// Safe: harness restores d_in from pristine before every launch.
__global__ __launch_bounds__(256) void repackW_kernel(float* __restrict__ w) {
    __shared__ float buf[4][KDIM];
    const int tid = threadIdx.x;
    const int l = tid & 63;
    const int wid = tid >> 6;
    const int row = blockIdx.x * 4 + wid;   // 0..767
    float* rowp = w + (size_t)row * KDIM;
#pragma unroll
    for (int i = 0; i < 19; ++i) {
        const int idx = i * 64 + l;
        if (idx < KDIM) buf[wid][idx] = rowp[idx];
    }
    __syncthreads();
    uint32_t* rowu = (uint32_t*)rowp;
#pragma unroll
    for (int i = 0; i < 10; ++i) {
        const int j = i * 64 + l;
        if (j < KDIM / 2) {
            const float f0 = buf[wid][2 * j], f1 = buf[wid][2 * j + 1];
            const uint32_t h0 = bf16_rn(f0), h1 = bf16_rn(f1);
            const uint32_t l0 = bf16_rn(f0 - bf16_tof(h0));
            const uint32_t l1 = bf16_rn(f1 - bf16_tof(h1));
            rowu[j]            = h0 | (h1 << 16);   // hi plane
            rowu[KDIM / 2 + j] = l0 | (l1 << 16);   // lo plane
        }
    }
}

// ---------------- Phase 2: GEMM — 32x32x16 MFMA, global_load_lds, 4 waves ----------------
// Block 128x64, 4 waves (2x2), wave tile 64x32 (2x1 of 32x32). BK=64.
// LDS 48KB -> 3 blocks/CU -> 12 waves/CU. Pre-swizzled global source (m173).
__global__ __launch_bounds__(256) void gemm_kernel(const uint8_t* __restrict__ A,
                                                   const uint8_t* __restrict__ Wp,
                                                   const float* __restrict__ bias,
                                                   float* __restrict__ out) {
    __shared__ uint8_t smem[49152];  // AsHi 16K | AsLo 16K | BsHi 8K | BsLo 8K

    const int tid = threadIdx.x;
    const int l = tid & 63;
    const int wid = tid >> 6;
    const int wm = wid >> 1, wn = wid & 1;

    // XCD-grouped decode: all 12 bn-blocks of a bm land on one XCD (bid%8)
    const int bid = blockIdx.x;
    const int xcd = bid & 7;
    const int t = bid >> 3;
    const int bn = t % 12;
    const int bm = (t / 12) * 8 + xcd;

    const int swzl = ((l & 7) * 16) ^ ((l >> 3) << 4);  // per-lane swizzled src byte
    const int xread = (l & 7) << 4;                     // frag-read XOR

    const uint8_t* Abase = A + (size_t)bm * 128 * ROW_BYTES;

    f32x16 acc[2] = {};

    for (int k0 = 0; k0 < KDIM; k0 += 64) {
        // ---- stage A hi+lo: 32KB ----
#pragma unroll
        for (int ii = 0; ii < 4; ++ii) {
            const int i = wid * 4 + ii;               // 0..15
            const int row = i * 8 + (l >> 3);         // 0..127
            const size_t gb = (size_t)row * ROW_BYTES + k0 * 2 + swzl;
            async_copy16(Abase + gb,        smem + i * 1024);           // hi
            async_copy16(Abase + gb + 2400, smem + 16384 + i * 1024);   // lo
        }
        // ---- stage B hi+lo: 16KB ----
#pragma unroll
        for (int ii = 0; ii < 2; ++ii) {
            const int i = wid * 2 + ii;               // 0..7
            const int row = i * 8 + (l >> 3);         // 0..63
            const size_t gb = (size_t)(bn * 64 + row) * ROW_BYTES + k0 * 2 + swzl;
            async_copy16(Wp + gb, smem + 32768 + i * 1024);             // hi
            size_t gl = gb + 2400;
            if (gl + 16 > (size_t)W_BYTES) gl = 0;    // last-row K-spill clamp (unused data)
            async_copy16(Wp + gl, smem + 40960 + i * 1024);             // lo
        }
        __syncthreads();

#pragma unroll
        for (int ks = 0; ks < 4; ++ks) {
            if (k0 + ks * 16 >= KDIM) break;          // K tail: skip garbage k>=1200
            const int koff = ks * 32 + ((l >> 5) * 16);
            short8b ahi[2], alo[2], bhi, blo;
#pragma unroll
            for (int mi = 0; mi < 2; ++mi) {
                const int row = wm * 64 + mi * 32 + (l & 31);
                const int byteA = row * 128 + (koff ^ xread);
                ahi[mi] = *(const short8b*)(smem + byteA);
                alo[mi] = *(const short8b*)(smem + 16384 + byteA);
            }
            {
                const int row = wn * 32 + (l & 31);
                const int byteB = row * 128 + (koff ^ xread);
                bhi = *(const short8b*)(smem + 32768 + byteB);
                blo = *(const short8b*)(smem + 40960 + byteB);
            }
#pragma unroll
            for (int mi = 0; mi < 2; ++mi) {
                acc[mi] = __builtin_amdgcn_mfma_f32_32x32x16_bf16(ahi[mi], bhi, acc[mi], 0, 0, 0);
                acc[mi] = __builtin_amdgcn_mfma_f32_32x32x16_bf16(ahi[mi], blo, acc[mi], 0, 0, 0);
                acc[mi] = __builtin_amdgcn_mfma_f32_32x32x16_bf16(alo[mi], bhi, acc[mi], 0, 0, 0);
            }
        }
        __syncthreads();
    }

    // epilogue: 32x32 C/D layout col=lane&31, row=(reg&3)+8*(reg>>2)+4*(lane>>5)
    const int e = bn * 64 + wn * 32 + (l & 31);
    const float bv = bias[e];
#pragma unroll
    for (int mi = 0; mi < 2; ++mi) {
        const int rbase = bm * 128 + wm * 64 + mi * 32 + 4 * (l >> 5);
#pragma unroll
        for (int r = 0; r < 16; ++r) {
            const int row = rbase + (r & 3) + 8 * (r >> 2);
            out[(size_t)row * EDIM + e] = acc[mi][r] + bv;
        }
    }
}

// ---------------- launcher ----------------
extern "C" void kernel_launch(void* const* d_in, const int* in_sizes, int n_in,
                              void* d_out, int out_size, void* d_ws, size_t ws_size,
                              hipStream_t stream) {
    const float* img      = (const float*)d_in[0];
    const int*   segments = (const int*)d_in[1];
    float*       proj_w   = (float*)d_in[2];        // repacked in place each launch
    const float* proj_b   = (const float*)d_in[3];
    float* out = (float*)d_out;

    uint8_t* apk = (uint8_t*)d_ws;
    int*     cnt = (int*)((char*)d_ws + APK_BYTES);

    hist_kernel<<<BATCH * NCHUNK, 256, 0, stream>>>(segments, cnt);
    scan_kernel<<<MROWS / 256, 256, 0, stream>>>(cnt);
    repackW_kernel<<<EDIM / 4, 256, 0, stream>>>(proj_w);
    scatter_kernel<<<BATCH * NCHUNK, 512, 0, stream>>>(img, segments, cnt, apk);
    tailzero_kernel<<<MROWS / 4, 256, 0, stream>>>(apk, cnt);

    gemm_kernel<<<64 * 12, 256, 0, stream>>>(apk, (const uint8_t*)proj_w, proj_b, out);
}

// Round 10
// 212.366 us; speedup vs baseline: 2.4676x; 1.0583x over previous
//
#include <hip/hip_runtime.h>
#include <hip/hip_bf16.h>
#include <cstdint>

// Problem constants (fixed by reference)
#define BATCH 32
#define NCH 3
#define HW 147456            // 384*384
#define NSEG 256
#define NPIX 400
#define KDIM 1200            // NCH*NPIX
#define EDIM 768
#define MROWS (BATCH * NSEG) // 8192

#define CHUNK 4096
#define NCHUNK (HW / CHUNK)  // 36
#define NW 16                // scatter waves/block (1024 threads)
#define SUBW (CHUNK / NW)    // 256 pixels per wave

#define ROW_BYTES 4800       // per (b,seg) row: [hi 2400B | lo 2400B] bf16 planes
#define APK_BYTES ((size_t)MROWS * ROW_BYTES)  // 39,321,600 (proven ws footprint)
#define W_BYTES (EDIM * KDIM * 4)              // 3,686,400

typedef __attribute__((ext_vector_type(8))) short short8b;   // 8 bf16
typedef __attribute__((ext_vector_type(16))) float f32x16;

// ---- split-bf16 helpers: v ~= hi + lo, each bf16 (RN) ----
__device__ __forceinline__ uint32_t bf16_rn(float f) {
    uint32_t u = __float_as_uint(f);
    return (u + 0x7fffu + ((u >> 16) & 1u)) >> 16;
}
__device__ __forceinline__ float bf16_tof(uint32_t h) { return __uint_as_float(h << 16); }
__device__ __forceinline__ uint32_t pack_split(float v) {
    uint32_t hi = bf16_rn(v);
    uint32_t lo = bf16_rn(v - bf16_tof(hi));
    return (lo << 16) | hi;
}

// async global->LDS, 16B/lane; LDS dest is wave-uniform base + lane*16 (m104);
// swizzle applied on per-lane GLOBAL source address (m173 pattern)
__device__ __forceinline__ void async_copy16(const void* gsrc, void* ldst) {
    __builtin_amdgcn_global_load_lds(
        (const __attribute__((address_space(1))) uint32_t*)gsrc,
        (__attribute__((address_space(3))) uint32_t*)ldst, 16, 0, 0);
}

// ---------------- Phase 1a: per-chunk histograms ----------------
__global__ __launch_bounds__(256) void hist_kernel(const int* __restrict__ seg,
                                                   int* __restrict__ cnt) {
    __shared__ int h[NSEG];
    const int tid = threadIdx.x;
    h[tid] = 0;
    __syncthreads();
    const int blk = blockIdx.x;
    const int b = blk / NCHUNK, ck = blk % NCHUNK;
    const int* segb = seg + (size_t)b * HW + ck * CHUNK;
#pragma unroll
    for (int i = 0; i < CHUNK / 256; ++i) atomicAdd(&h[segb[i * 256 + tid]], 1);
    __syncthreads();
    cnt[blk * NSEG + tid] = h[tid];
}

// ---------------- Phase 1b: exclusive scan over chunks per (b, s) ----------------
// v2: all 36 loads issued before use (1 wait instead of 36 dependent trips).
// Grand total is stored into the chunk-0 slot (base always 0, special-cased).
__global__ __launch_bounds__(256) void scan_kernel(int* __restrict__ cnt) {
    const int t = blockIdx.x * 256 + threadIdx.x;
    const int b = t >> 8, s = t & 255;
    int* basep = cnt + (size_t)(b * NCHUNK) * NSEG + s;
    int v[NCHUNK];
#pragma unroll
    for (int ck = 0; ck < NCHUNK; ++ck) v[ck] = basep[ck * NSEG];
    int run = 0;
#pragma unroll
    for (int ck = 0; ck < NCHUNK; ++ck) { const int x = v[ck]; v[ck] = run; run += x; }
    v[0] = run;   // chunk-0 base is always 0; slot repurposed for grand total
#pragma unroll
    for (int ck = 0; ck < NCHUNK; ++ck) basep[ck * NSEG] = v[ck];
}

// ---------------- Phase 1c: scatter v6 — 16 waves, LDS sort, direct plane writeout ----------------
// 16 waves x 256-pixel sequential sub-chunks (stable). 70KB LDS -> 2 blocks/CU
// = 32 waves/CU (full slots). Single-wave shfl scan (3 barriers total around it).
// segmap kills the writeout binary search.
__global__ __launch_bounds__(1024) void scatter_kernel(const float* __restrict__ img,
                                                       const int* __restrict__ seg,
                                                       const int* __restrict__ base,
                                                       uint8_t* __restrict__ apk) {
    __shared__ int wpos[NW][NSEG];     // 16 KB: counts -> per-wave cursors
    __shared__ int sbv[NSEG];          // 1 KB: chunk base per seg
    __shared__ int sl[NSEG];           // 1 KB: csum -> packed (sbase<<13)|lb
    __shared__ uint8_t segmap[CHUNK];  // 4 KB: slot -> seg
    __shared__ uint32_t st0[CHUNK], st1[CHUNK], st2[CHUNK]; // 48 KB staging

    const int tid = threadIdx.x;
    const int lane = tid & 63;
    const int wid = tid >> 6;
    const int blk = blockIdx.x;
    const int b = blk / NCHUNK, ck = blk % NCHUNK;

    if (tid < NSEG) sbv[tid] = (ck == 0) ? 0 : base[(size_t)blk * NSEG + tid];
#pragma unroll
    for (int i = 0; i < (NW * NSEG) / 1024; ++i) ((int*)wpos)[i * 1024 + tid] = 0;
    __syncthreads();

    const int* segb = seg + (size_t)b * HW;
    const float* imgb = img + (size_t)b * NCH * HW;
    const int startp = ck * CHUNK + wid * SUBW;
    const unsigned long long lt = (lane == 0) ? 0ull : ((~0ull) >> (64 - lane));

    int sv[SUBW / 64];
    unsigned long long mv[SUBW / 64];
    // pass 1: per-wave per-segment counts (waves own disjoint sequential ranges)
#pragma unroll
    for (int g = 0; g < SUBW / 64; ++g) {
        const int p = startp + g * 64 + lane;
        const int s = segb[p];
        unsigned long long m = ~0ull;
#pragma unroll
        for (int bit = 0; bit < 8; ++bit) {
            unsigned long long bal = __ballot((s >> bit) & 1);
            m &= ((s >> bit) & 1) ? bal : ~bal;
        }
        sv[g] = s; mv[g] = m;
        if ((m & lt) == 0ull) atomicAdd(&wpos[wid][s], __popcll(m));
    }
    __syncthreads();

    // counts -> per-wave global cursors; chunk count per seg into sl
    if (tid < NSEG) {
        int r = sbv[tid];
#pragma unroll
        for (int w = 0; w < NW; ++w) {
            const int t = wpos[w][tid];
            wpos[w][tid] = r;
            r += t;
        }
        sl[tid] = r - sbv[tid];   // csum
    }
    __syncthreads();

    // single-wave exclusive scan of sl (4 segs/lane, shfl_up across 64 lanes)
    if (wid == 0) {
        int v0 = sl[lane * 4], v1 = sl[lane * 4 + 1], v2 = sl[lane * 4 + 2], v3 = sl[lane * 4 + 3];
        const int mysum = v0 + v1 + v2 + v3;
        int run = mysum;
#pragma unroll
        for (int off = 1; off < 64; off <<= 1) {
            const int y = __shfl_up(run, off, 64);
            if (lane >= off) run += y;
        }
        int e = run - mysum;   // exclusive base for this lane's 4 segs
        sl[lane * 4]     = (sbv[lane * 4]     << 13) | e;  e += v0;
        sl[lane * 4 + 1] = (sbv[lane * 4 + 1] << 13) | e;  e += v1;
        sl[lane * 4 + 2] = (sbv[lane * 4 + 2] << 13) | e;  e += v2;
        sl[lane * 4 + 3] = (sbv[lane * 4 + 3] << 13) | e;
    }
    __syncthreads();

    // pass 2: assign ranks (stable), stage packed split-bf16 at chunk-sorted slot j
#pragma unroll
    for (int g = 0; g < SUBW / 64; ++g) {
        const int p = startp + g * 64 + lane;
        const int s = sv[g];
        const unsigned long long m = mv[g];
        const int rig = __popcll(m & lt);
        const int leader = __ffsll((unsigned long long)m) - 1;
        int old = 0;
        if (rig == 0) old = atomicAdd(&wpos[wid][s], __popcll(m));
        old = __shfl(old, leader, 64);
        const int rank = old + rig;                  // global rank in segment
        const int v = sl[s];
        const int j = rank - (v >> 13) + (v & 8191); // chunk-local sorted slot
        st0[j] = pack_split(imgb[p]);
        st1[j] = pack_split(imgb[HW + p]);
        st2[j] = pack_split(imgb[2 * HW + p]);
        segmap[j] = (uint8_t)s;
    }
    __syncthreads();

    // writeout: linear slots; 6 contiguous u16 stores/slot into [hi|lo] planes
    uint8_t* apkb = apk + (size_t)b * NSEG * ROW_BYTES;
#pragma unroll
    for (int it = 0; it < CHUNK / 1024; ++it) {
        const int j = it * 1024 + tid;
        const int s = segmap[j];
        const int v = sl[s];
        const int rank = (v >> 13) + (j - (v & 8191));
        if (rank < NPIX) {
            uint16_t* hp = (uint16_t*)(apkb + (size_t)s * ROW_BYTES);
            uint16_t* lp = (uint16_t*)(apkb + (size_t)s * ROW_BYTES + 2400);
            const uint32_t v0 = st0[j], v1 = st1[j], v2 = st2[j];
            hp[rank]       = (uint16_t)v0;  lp[rank]       = (uint16_t)(v0 >> 16);
            hp[400 + rank] = (uint16_t)v1;  lp[400 + rank] = (uint16_t)(v1 >> 16);
            hp[800 + rank] = (uint16_t)v2;  lp[800 + rank] = (uint16_t)(v2 >> 16);
        }
    }
}

// ---------------- Phase 1d: tail-zero (rare: segments with < 400 pixels) ----------------
__global__ __launch_bounds__(256) void tailzero_kernel(uint8_t* __restrict__ apk,
                                                       const int* __restrict__ cnt) {
    const int tid = threadIdx.x;
    const int l = tid & 63;
    const int wid = tid >> 6;
    const int row = blockIdx.x * 4 + wid;   // 0..8191
    const int b = row >> 8, s = row & 255;
    const int tot = cnt[(size_t)(b * NCHUNK) * NSEG + s];
    if (tot >= NPIX) return;                // wave-uniform
    uint16_t* hp = (uint16_t*)(apk + (size_t)row * ROW_BYTES);
    uint16_t* lp = (uint16_t*)(apk + (size_t)row * ROW_BYTES + 2400);
    for (int r = tot + l; r < NPIX; r += 64) {
        hp[r] = 0; lp[r] = 0;
        hp[400 + r] = 0; lp[400 + r] = 0;
        hp[800 + r] = 0; lp[800 + r] = 0;
    }
}

// ---------------- Phase 1e: repack W in place: f32 -> [hi|lo] bf16 planes ----------------
// Safe: harness restores d_in from pristine before every launch.
__global__ __launch_bounds__(256) void repackW_kernel(float* __restrict__ w) {
    __shared__ float buf[4][KDIM];
    const int tid = threadIdx.x;
    const int l = tid & 63;
    const int wid = tid >> 6;
    const int row = blockIdx.x * 4 + wid;   // 0..767
    float* rowp = w + (size_t)row * KDIM;
#pragma unroll
    for (int i = 0; i < 19; ++i) {
        const int idx = i * 64 + l;
        if (idx < KDIM) buf[wid][idx] = rowp[idx];
    }
    __syncthreads();
    uint32_t* rowu = (uint32_t*)rowp;
#pragma unroll
    for (int i = 0; i < 10; ++i) {
        const int j = i * 64 + l;
        if (j < KDIM / 2) {
            const float f0 = buf[wid][2 * j], f1 = buf[wid][2 * j + 1];
            const uint32_t h0 = bf16_rn(f0), h1 = bf16_rn(f1);
            const uint32_t l0 = bf16_rn(f0 - bf16_tof(h0));
            const uint32_t l1 = bf16_rn(f1 - bf16_tof(h1));
            rowu[j]            = h0 | (h1 << 16);   // hi plane
            rowu[KDIM / 2 + j] = l0 | (l1 << 16);   // lo plane
        }
    }
}

// ---------------- Phase 2: GEMM — 32x32x16 MFMA, global_load_lds, 4 waves ----------------
// Block 128x64, 4 waves (2x2), wave tile 64x32 (2x1 of 32x32). BK=64.
// LDS 48KB -> 3 blocks/CU -> 12 waves/CU. Pre-swizzled global source (m173).
__global__ __launch_bounds__(256) void gemm_kernel(const uint8_t* __restrict__ A,
                                                   const uint8_t* __restrict__ Wp,
                                                   const float* __restrict__ bias,
                                                   float* __restrict__ out) {
    __shared__ uint8_t smem[49152];  // AsHi 16K | AsLo 16K | BsHi 8K | BsLo 8K

    const int tid = threadIdx.x;
    const int l = tid & 63;
    const int wid = tid >> 6;
    const int wm = wid >> 1, wn = wid & 1;

    // XCD-grouped decode: all 12 bn-blocks of a bm land on one XCD (bid%8)
    const int bid = blockIdx.x;
    const int xcd = bid & 7;
    const int t = bid >> 3;
    const int bn = t % 12;
    const int bm = (t / 12) * 8 + xcd;

    const int swzl = ((l & 7) * 16) ^ ((l >> 3) << 4);  // per-lane swizzled src byte
    const int xread = (l & 7) << 4;                     // frag-read XOR

    const uint8_t* Abase = A + (size_t)bm * 128 * ROW_BYTES;

    f32x16 acc[2] = {};

    for (int k0 = 0; k0 < KDIM; k0 += 64) {
        // ---- stage A hi+lo: 32KB ----
#pragma unroll
        for (int ii = 0; ii < 4; ++ii) {
            const int i = wid * 4 + ii;               // 0..15
            const int row = i * 8 + (l >> 3);         // 0..127
            const size_t gb = (size_t)row * ROW_BYTES + k0 * 2 + swzl;
            async_copy16(Abase + gb,        smem + i * 1024);           // hi
            async_copy16(Abase + gb + 2400, smem + 16384 + i * 1024);   // lo
        }
        // ---- stage B hi+lo: 16KB ----
#pragma unroll
        for (int ii = 0; ii < 2; ++ii) {
            const int i = wid * 2 + ii;               // 0..7
            const int row = i * 8 + (l >> 3);         // 0..63
            const size_t gb = (size_t)(bn * 64 + row) * ROW_BYTES + k0 * 2 + swzl;
            async_copy16(Wp + gb, smem + 32768 + i * 1024);             // hi
            size_t gl = gb + 2400;
            if (gl + 16 > (size_t)W_BYTES) gl = 0;    // last-row K-spill clamp (unused data)
            async_copy16(Wp + gl, smem + 40960 + i * 1024);             // lo
        }
        __syncthreads();

#pragma unroll
        for (int ks = 0; ks < 4; ++ks) {
            if (k0 + ks * 16 >= KDIM) break;          // K tail: skip garbage k>=1200
            const int koff = ks * 32 + ((l >> 5) * 16);
            short8b ahi[2], alo[2], bhi, blo;
#pragma unroll
            for (int mi = 0; mi < 2; ++mi) {
                const int row = wm * 64 + mi * 32 + (l & 31);
                const int byteA = row * 128 + (koff ^ xread);
                ahi[mi] = *(const short8b*)(smem + byteA);
                alo[mi] = *(const short8b*)(smem + 16384 + byteA);
            }
            {
                const int row = wn * 32 + (l & 31);
                const int byteB = row * 128 + (koff ^ xread);
                bhi = *(const short8b*)(smem + 32768 + byteB);
                blo = *(const short8b*)(smem + 40960 + byteB);
            }
#pragma unroll
            for (int mi = 0; mi < 2; ++mi) {
                acc[mi] = __builtin_amdgcn_mfma_f32_32x32x16_bf16(ahi[mi], bhi, acc[mi], 0, 0, 0);
                acc[mi] = __builtin_amdgcn_mfma_f32_32x32x16_bf16(ahi[mi], blo, acc[mi], 0, 0, 0);
                acc[mi] = __builtin_amdgcn_mfma_f32_32x32x16_bf16(alo[mi], bhi, acc[mi], 0, 0, 0);
            }
        }
        __syncthreads();
    }

    // epilogue: 32x32 C/D layout col=lane&31, row=(reg&3)+8*(reg>>2)+4*(lane>>5)
    const int e = bn * 64 + wn * 32 + (l & 31);
    const float bv = bias[e];
#pragma unroll
    for (int mi = 0; mi < 2; ++mi) {
        const int rbase = bm * 128 + wm * 64 + mi * 32 + 4 * (l >> 5);
#pragma unroll
        for (int r = 0; r < 16; ++r) {
            const int row = rbase + (r & 3) + 8 * (r >> 2);
            out[(size_t)row * EDIM + e] = acc[mi][r] + bv;
        }
    }
}

// ---------------- launcher ----------------
extern "C" void kernel_launch(void* const* d_in, const int* in_sizes, int n_in,
                              void* d_out, int out_size, void* d_ws, size_t ws_size,
                              hipStream_t stream) {
    const float* img      = (const float*)d_in[0];
    const int*   segments = (const int*)d_in[1];
    float*       proj_w   = (float*)d_in[2];        // repacked in place each launch
    const float* proj_b   = (const float*)d_in[3];
    float* out = (float*)d_out;

    uint8_t* apk = (uint8_t*)d_ws;
    int*     cnt = (int*)((char*)d_ws + APK_BYTES);

    hist_kernel<<<BATCH * NCHUNK, 256, 0, stream>>>(segments, cnt);
    scan_kernel<<<MROWS / 256, 256, 0, stream>>>(cnt);
    repackW_kernel<<<EDIM / 4, 256, 0, stream>>>(proj_w);
    scatter_kernel<<<BATCH * NCHUNK, 1024, 0, stream>>>(img, segments, cnt, apk);
    tailzero_kernel<<<MROWS / 4, 256, 0, stream>>>(apk, cnt);

    gemm_kernel<<<64 * 12, 256, 0, stream>>>(apk, (const uint8_t*)proj_w, proj_b, out);
}

// Round 11
// 210.310 us; speedup vs baseline: 2.4917x; 1.0098x over previous
//
#include <hip/hip_runtime.h>
#include <hip/hip_bf16.h>
#include <cstdint>

// Problem constants (fixed by reference)
#define BATCH 32
#define NCH 3
#define HW 147456            // 384*384
#define NSEG 256
#define NPIX 400
#define KDIM 1200            // NCH*NPIX
#define EDIM 768
#define MROWS (BATCH * NSEG) // 8192

#define CHUNK 4096
#define NCHUNK (HW / CHUNK)  // 36
#define NW 16                // scatter waves/block (1024 threads)
#define SUBW (CHUNK / NW)    // 256 pixels per wave
#define HIST_BLOCKS (BATCH * NCHUNK)   // 1152

#define ROW_BYTES 4800       // per (b,seg) row: [hi 2400B | lo 2400B] bf16 planes
#define APK_BYTES ((size_t)MROWS * ROW_BYTES)  // 39,321,600 (proven ws footprint)
#define W_BYTES (EDIM * KDIM * 4)              // 3,686,400

typedef __attribute__((ext_vector_type(8))) short short8b;   // 8 bf16
typedef __attribute__((ext_vector_type(16))) float f32x16;

// ---- split-bf16 helpers: v ~= hi + lo, each bf16 (RN) ----
__device__ __forceinline__ uint32_t bf16_rn(float f) {
    uint32_t u = __float_as_uint(f);
    return (u + 0x7fffu + ((u >> 16) & 1u)) >> 16;
}
__device__ __forceinline__ float bf16_tof(uint32_t h) { return __uint_as_float(h << 16); }
__device__ __forceinline__ uint32_t pack_split(float v) {
    uint32_t hi = bf16_rn(v);
    uint32_t lo = bf16_rn(v - bf16_tof(hi));
    return (lo << 16) | hi;
}

// async global->LDS, 16B/lane; LDS dest is wave-uniform base + lane*16 (m104);
// swizzle applied on per-lane GLOBAL source address (m173 pattern)
__device__ __forceinline__ void async_copy16(const void* gsrc, void* ldst) {
    __builtin_amdgcn_global_load_lds(
        (const __attribute__((address_space(1))) uint32_t*)gsrc,
        (__attribute__((address_space(3))) uint32_t*)ldst, 16, 0, 0);
}

// ---------------- Phase 1a: hist (wave-private) + repackW, horizontally fused ----------------
__global__ __launch_bounds__(256) void histW_kernel(const int* __restrict__ seg,
                                                    int* __restrict__ cnt,
                                                    float* __restrict__ w) {
    __shared__ uint32_t sbuf[4 * KDIM];   // 19200 B union
    const int tid = threadIdx.x;
    const int l = tid & 63;
    const int wid = tid >> 6;

    if (blockIdx.x < HIST_BLOCKS) {
        // ---- per-chunk histogram, wave-private to cut atomic contention ----
        int* h = (int*)sbuf;              // h[4][NSEG]
#pragma unroll
        for (int i = 0; i < 4; ++i) h[i * NSEG + tid] = 0;
        __syncthreads();
        const int blk = blockIdx.x;
        const int b = blk / NCHUNK, ck = blk % NCHUNK;
        const int* segb = seg + (size_t)b * HW + ck * CHUNK;
#pragma unroll
        for (int i = 0; i < CHUNK / 256; ++i)
            atomicAdd(&h[wid * NSEG + segb[i * 256 + tid]], 1);
        __syncthreads();
        cnt[blk * NSEG + tid] = h[tid] + h[NSEG + tid] + h[2 * NSEG + tid] + h[3 * NSEG + tid];
    } else {
        // ---- repack W in place: f32 -> [hi|lo] bf16 planes (harness restores d_in) ----
        float* buf = (float*)sbuf;        // buf[4][KDIM]
        const int row = (blockIdx.x - HIST_BLOCKS) * 4 + wid;   // 0..767
        float* rowp = w + (size_t)row * KDIM;
#pragma unroll
        for (int i = 0; i < 19; ++i) {
            const int idx = i * 64 + l;
            if (idx < KDIM) buf[wid * KDIM + idx] = rowp[idx];
        }
        __syncthreads();
        uint32_t* rowu = (uint32_t*)rowp;
#pragma unroll
        for (int i = 0; i < 10; ++i) {
            const int j = i * 64 + l;
            if (j < KDIM / 2) {
                const float f0 = buf[wid * KDIM + 2 * j], f1 = buf[wid * KDIM + 2 * j + 1];
                const uint32_t h0 = bf16_rn(f0), h1 = bf16_rn(f1);
                const uint32_t l0 = bf16_rn(f0 - bf16_tof(h0));
                const uint32_t l1 = bf16_rn(f1 - bf16_tof(h1));
                rowu[j]            = h0 | (h1 << 16);   // hi plane
                rowu[KDIM / 2 + j] = l0 | (l1 << 16);   // lo plane
            }
        }
    }
}

// ---------------- Phase 1b: exclusive scan over chunks per (b, s) ----------------
// All 36 loads issued before use. Grand total stored into the chunk-0 slot.
__global__ __launch_bounds__(256) void scan_kernel(int* __restrict__ cnt) {
    const int t = blockIdx.x * 256 + threadIdx.x;
    const int b = t >> 8, s = t & 255;
    int* basep = cnt + (size_t)(b * NCHUNK) * NSEG + s;
    int v[NCHUNK];
#pragma unroll
    for (int ck = 0; ck < NCHUNK; ++ck) v[ck] = basep[ck * NSEG];
    int run = 0;
#pragma unroll
    for (int ck = 0; ck < NCHUNK; ++ck) { const int x = v[ck]; v[ck] = run; run += x; }
    v[0] = run;   // chunk-0 base is always 0; slot repurposed for grand total
#pragma unroll
    for (int ck = 0; ck < NCHUNK; ++ck) basep[ck * NSEG] = v[ck];
}

// ---------------- Phase 1c: scatter v6 + fused tail-zero ----------------
__global__ __launch_bounds__(1024) void scatter_kernel(const float* __restrict__ img,
                                                       const int* __restrict__ seg,
                                                       const int* __restrict__ base,
                                                       uint8_t* __restrict__ apk) {
    __shared__ int wpos[NW][NSEG];     // 16 KB
    __shared__ int sbv[NSEG];          // 1 KB
    __shared__ int sl[NSEG];           // 1 KB
    __shared__ uint8_t segmap[CHUNK];  // 4 KB
    __shared__ uint32_t st0[CHUNK], st1[CHUNK], st2[CHUNK]; // 48 KB

    const int tid = threadIdx.x;
    const int lane = tid & 63;
    const int wid = tid >> 6;
    const int blk = blockIdx.x;
    const int b = blk / NCHUNK, ck = blk % NCHUNK;

    if (tid < NSEG) sbv[tid] = (ck == 0) ? 0 : base[(size_t)blk * NSEG + tid];
#pragma unroll
    for (int i = 0; i < (NW * NSEG) / 1024; ++i) ((int*)wpos)[i * 1024 + tid] = 0;
    __syncthreads();

    const int* segb = seg + (size_t)b * HW;
    const float* imgb = img + (size_t)b * NCH * HW;
    const int startp = ck * CHUNK + wid * SUBW;
    const unsigned long long lt = (lane == 0) ? 0ull : ((~0ull) >> (64 - lane));

    int sv[SUBW / 64];
    unsigned long long mv[SUBW / 64];
#pragma unroll
    for (int g = 0; g < SUBW / 64; ++g) {
        const int p = startp + g * 64 + lane;
        const int s = segb[p];
        unsigned long long m = ~0ull;
#pragma unroll
        for (int bit = 0; bit < 8; ++bit) {
            unsigned long long bal = __ballot((s >> bit) & 1);
            m &= ((s >> bit) & 1) ? bal : ~bal;
        }
        sv[g] = s; mv[g] = m;
        if ((m & lt) == 0ull) atomicAdd(&wpos[wid][s], __popcll(m));
    }
    __syncthreads();

    if (tid < NSEG) {
        int r = sbv[tid];
#pragma unroll
        for (int w = 0; w < NW; ++w) {
            const int t = wpos[w][tid];
            wpos[w][tid] = r;
            r += t;
        }
        sl[tid] = r - sbv[tid];   // csum
    }
    __syncthreads();

    // single-wave exclusive scan of sl (4 segs/lane)
    if (wid == 0) {
        int v0 = sl[lane * 4], v1 = sl[lane * 4 + 1], v2 = sl[lane * 4 + 2], v3 = sl[lane * 4 + 3];
        const int mysum = v0 + v1 + v2 + v3;
        int run = mysum;
#pragma unroll
        for (int off = 1; off < 64; off <<= 1) {
            const int y = __shfl_up(run, off, 64);
            if (lane >= off) run += y;
        }
        int e = run - mysum;
        sl[lane * 4]     = (sbv[lane * 4]     << 13) | e;  e += v0;
        sl[lane * 4 + 1] = (sbv[lane * 4 + 1] << 13) | e;  e += v1;
        sl[lane * 4 + 2] = (sbv[lane * 4 + 2] << 13) | e;  e += v2;
        sl[lane * 4 + 3] = (sbv[lane * 4 + 3] << 13) | e;
    }
    __syncthreads();

#pragma unroll
    for (int g = 0; g < SUBW / 64; ++g) {
        const int p = startp + g * 64 + lane;
        const int s = sv[g];
        const unsigned long long m = mv[g];
        const int rig = __popcll(m & lt);
        const int leader = __ffsll((unsigned long long)m) - 1;
        int old = 0;
        if (rig == 0) old = atomicAdd(&wpos[wid][s], __popcll(m));
        old = __shfl(old, leader, 64);
        const int rank = old + rig;
        const int v = sl[s];
        const int j = rank - (v >> 13) + (v & 8191);
        st0[j] = pack_split(imgb[p]);
        st1[j] = pack_split(imgb[HW + p]);
        st2[j] = pack_split(imgb[2 * HW + p]);
        segmap[j] = (uint8_t)s;
    }
    __syncthreads();

    uint8_t* apkb = apk + (size_t)b * NSEG * ROW_BYTES;
#pragma unroll
    for (int it = 0; it < CHUNK / 1024; ++it) {
        const int j = it * 1024 + tid;
        const int s = segmap[j];
        const int v = sl[s];
        const int rank = (v >> 13) + (j - (v & 8191));
        if (rank < NPIX) {
            uint16_t* hp = (uint16_t*)(apkb + (size_t)s * ROW_BYTES);
            uint16_t* lp = (uint16_t*)(apkb + (size_t)s * ROW_BYTES + 2400);
            const uint32_t v0 = st0[j], v1 = st1[j], v2 = st2[j];
            hp[rank]       = (uint16_t)v0;  lp[rank]       = (uint16_t)(v0 >> 16);
            hp[400 + rank] = (uint16_t)v1;  lp[400 + rank] = (uint16_t)(v1 >> 16);
            hp[800 + rank] = (uint16_t)v2;  lp[800 + rank] = (uint16_t)(v2 >> 16);
        }
    }

    // fused tail-zero (rare: seg with < 400 px); tails are disjoint bytes from
    // every writeout store, so no barrier/race. Grand total from chunk-0 slot.
    if (ck == NCHUNK - 1 && tid < NSEG) {
        const int tot = base[(size_t)(b * NCHUNK) * NSEG + tid];
        if (tot < NPIX) {
            uint16_t* hp = (uint16_t*)(apkb + (size_t)tid * ROW_BYTES);
            uint16_t* lp = (uint16_t*)(apkb + (size_t)tid * ROW_BYTES + 2400);
            for (int r = tot; r < NPIX; ++r) {
                hp[r] = 0; lp[r] = 0;
                hp[400 + r] = 0; lp[400 + r] = 0;
                hp[800 + r] = 0; lp[800 + r] = 0;
            }
        }
    }
}

// ---------------- Phase 2: GEMM v4 — 2-phase dbuf pipeline, counted vmcnt (T3+T4) ----------------
// Block 128x64, 4 waves (2x2), wave tile 64x32. BK=32, NT=38 K-steps.
// LDS 2 x 24KB -> 3 blocks/CU. Per iter: issue STAGE(t+1) -> vmcnt(6) (tile t
// landed, t+1 stays in flight) -> raw barrier -> MFMA -> raw barrier. Never
// drains vmcnt to 0 in the loop (the m97-structure stall this replaces).
#define NT 38
#define BUF_BYTES 24576

__global__ __launch_bounds__(256) void gemm_kernel(const uint8_t* __restrict__ A,
                                                   const uint8_t* __restrict__ Wp,
                                                   const float* __restrict__ bias,
                                                   float* __restrict__ out) {
    __shared__ uint8_t smem[2 * BUF_BYTES];  // per buf: AsHi 8K | AsLo 8K | BsHi 4K | BsLo 4K

    const int tid = threadIdx.x;
    const int l = tid & 63;
    const int wid = tid >> 6;
    const int wm = wid >> 1, wn = wid & 1;

    // XCD-grouped decode: all 12 bn-blocks of a bm land on one XCD (bid%8)
    const int bid = blockIdx.x;
    const int xcd = bid & 7;
    const int tq = bid >> 3;
    const int bn = tq % 12;
    const int bm = (tq / 12) * 8 + xcd;

    // staging: copy-block = 16 rows x 64B; lane l -> row_local l>>2, src chunk (l&3)^((l>>3)&3)
    const int csrc = ((l & 3) ^ ((l >> 3) & 3)) * 16;
    const int rl4 = l >> 2;
    // frag reads: row bits 1-2 give the XOR (bank spread over 8 groups)
    const int lr31 = l & 31;
    const int kcb = l >> 5;              // 0/1: k-slice within K=16... selects 16B chunk
    const int fA = (lr31 >> 1) & 3;

    const uint8_t* Abase = A + (size_t)bm * 128 * ROW_BYTES;
    const uint8_t* Bbase = Wp + (size_t)bn * 64 * ROW_BYTES;

    f32x16 acc[2] = {};

#define STAGE(t_, q_)                                                                   \
    {                                                                                   \
        const int k2 = (t_) * 64;                                                       \
        uint8_t* bufb = smem + (q_) * BUF_BYTES;                                        \
        _Pragma("unroll")                                                               \
        for (int ii = 0; ii < 2; ++ii) {                                                \
            const int i = wid * 2 + ii;                                                 \
            const size_t gb = (size_t)(i * 16 + rl4) * ROW_BYTES + k2 + csrc;           \
            async_copy16(Abase + gb,        bufb + i * 1024);                           \
            async_copy16(Abase + gb + 2400, bufb + 8192 + i * 1024);                    \
        }                                                                               \
        {                                                                               \
            const int row = wid * 16 + rl4;                                             \
            const size_t gb = (size_t)row * ROW_BYTES + k2 + csrc;                      \
            async_copy16(Bbase + gb, bufb + 16384 + wid * 1024);                        \
            size_t gl = (size_t)(bn * 64 + row) * ROW_BYTES + k2 + csrc + 2400;         \
            if (gl + 16 > (size_t)W_BYTES) gl = 0; /* last-row spill, data unused */    \
            async_copy16(Wp + gl, bufb + 20480 + wid * 1024);                           \
        }                                                                               \
    }

    STAGE(0, 0)
    for (int t = 0; t < NT; ++t) {
        if (t + 1 < NT) {
            STAGE(t + 1, (t + 1) & 1)
            asm volatile("s_waitcnt vmcnt(6)" ::: "memory");   // tile t landed; t+1 in flight
        } else {
            asm volatile("s_waitcnt vmcnt(0)" ::: "memory");
        }
        __builtin_amdgcn_sched_barrier(0);
        __builtin_amdgcn_s_barrier();

        {
            uint8_t* bufb = smem + (t & 1) * BUF_BYTES;
            const int k0 = t * 32;
#pragma unroll
            for (int ks = 0; ks < 2; ++ks) {
                if (k0 + ks * 16 >= KDIM) break;     // K tail: skip k>=1200
                const int cc = 16 * ((2 * ks + kcb) ^ fA);
                short8b ahi[2], alo[2], bhi, blo;
#pragma unroll
                for (int mi = 0; mi < 2; ++mi) {
                    const int ro = (wm * 64 + mi * 32 + lr31) * 64;
                    ahi[mi] = *(const short8b*)(bufb + ro + cc);
                    alo[mi] = *(const short8b*)(bufb + 8192 + ro + cc);
                }
                {
                    const int ro = (wn * 32 + lr31) * 64;
                    bhi = *(const short8b*)(bufb + 16384 + ro + cc);
                    blo = *(const short8b*)(bufb + 20480 + ro + cc);
                }
#pragma unroll
                for (int mi = 0; mi < 2; ++mi) {
                    acc[mi] = __builtin_amdgcn_mfma_f32_32x32x16_bf16(ahi[mi], bhi, acc[mi], 0, 0, 0);
                    acc[mi] = __builtin_amdgcn_mfma_f32_32x32x16_bf16(ahi[mi], blo, acc[mi], 0, 0, 0);
                    acc[mi] = __builtin_amdgcn_mfma_f32_32x32x16_bf16(alo[mi], bhi, acc[mi], 0, 0, 0);
                }
            }
        }
        __builtin_amdgcn_s_barrier();   // all waves done reading buf[t&1] before it's restaged
    }
#undef STAGE

    // epilogue: 32x32 C/D layout col=lane&31, row=(reg&3)+8*(reg>>2)+4*(lane>>5)
    const int e = bn * 64 + wn * 32 + (l & 31);
    const float bv = bias[e];
#pragma unroll
    for (int mi = 0; mi < 2; ++mi) {
        const int rbase = bm * 128 + wm * 64 + mi * 32 + 4 * (l >> 5);
#pragma unroll
        for (int r = 0; r < 16; ++r) {
            const int row = rbase + (r & 3) + 8 * (r >> 2);
            out[(size_t)row * EDIM + e] = acc[mi][r] + bv;
        }
    }
}

// ---------------- launcher ----------------
extern "C" void kernel_launch(void* const* d_in, const int* in_sizes, int n_in,
                              void* d_out, int out_size, void* d_ws, size_t ws_size,
                              hipStream_t stream) {
    const float* img      = (const float*)d_in[0];
    const int*   segments = (const int*)d_in[1];
    float*       proj_w   = (float*)d_in[2];        // repacked in place each launch
    const float* proj_b   = (const float*)d_in[3];
    float* out = (float*)d_out;

    uint8_t* apk = (uint8_t*)d_ws;
    int*     cnt = (int*)((char*)d_ws + APK_BYTES);

    histW_kernel<<<HIST_BLOCKS + EDIM / 4, 256, 0, stream>>>(segments, cnt, proj_w);
    scan_kernel<<<MROWS / 256, 256, 0, stream>>>(cnt);
    scatter_kernel<<<BATCH * NCHUNK, 1024, 0, stream>>>(img, segments, cnt, apk);

    gemm_kernel<<<64 * 12, 256, 0, stream>>>(apk, (const uint8_t*)proj_w, proj_b, out);
}